// Round 1
// baseline (989.064 us; speedup 1.0000x reference)
//
#include <hip/hip_runtime.h>
#include <stdint.h>

#define FC    256
#define HH    512
#define MX    1024
#define LASTN 128
#define NROW  16384
#define NGRP  2048

__device__ __forceinline__ float wave_sum64(float v) {
#pragma unroll
  for (int m = 1; m < 64; m <<= 1) v += __shfl_xor(v, m);
  return v;
}
__device__ __forceinline__ float wave_sum32(float v) {
#pragma unroll
  for (int m = 1; m < 32; m <<= 1) v += __shfl_xor(v, m);
  return v;
}

__device__ __forceinline__ void unpack8(uint4 u, float* a) {
  a[0] = __uint_as_float(u.x << 16);
  a[1] = __uint_as_float(u.x & 0xffff0000u);
  a[2] = __uint_as_float(u.y << 16);
  a[3] = __uint_as_float(u.y & 0xffff0000u);
  a[4] = __uint_as_float(u.z << 16);
  a[5] = __uint_as_float(u.z & 0xffff0000u);
  a[6] = __uint_as_float(u.w << 16);
  a[7] = __uint_as_float(u.w & 0xffff0000u);
}

// ---------------- Kernel 1: s1 = relu(LN(state @ enc_w + enc_b)) ----------------
__global__ __launch_bounds__(256) void k_enc(
    const float* __restrict__ state, const float* __restrict__ enc_w,
    const float* __restrict__ enc_b, const float* __restrict__ enc_g,
    const float* __restrict__ enc_bb, float* __restrict__ s1)
{
  __shared__ float smA[32 * 36];
  __shared__ float smB[32 * 260];
  const int tid = threadIdx.x;
  const int tr = tid >> 6;        // wave 0..3 -> rows tr*8..tr*8+7
  const int tc = tid & 63;        // cols tc*4..tc*4+3
  const int row0 = blockIdx.x * 32;
  const int c4 = tc * 4;
  float acc[8][4];
#pragma unroll
  for (int r = 0; r < 8; ++r) { acc[r][0]=acc[r][1]=acc[r][2]=acc[r][3]=0.f; }
  const int ka = tid & 31, ra = tid >> 5;
  const int kb = tid >> 6;
  for (int kc = 0; kc < 16; ++kc) {
    const int k0 = kc * 32;
    __syncthreads();
#pragma unroll
    for (int i = 0; i < 4; ++i) {
      int r = ra + i * 8;
      smA[ka * 36 + r] = state[(size_t)(row0 + r) * HH + k0 + ka];
    }
#pragma unroll
    for (int i = 0; i < 8; ++i) {
      int kk = kb + i * 4;
      *(float4*)&smB[kk * 260 + c4] = *(const float4*)&enc_w[(size_t)(k0 + kk) * FC + c4];
    }
    __syncthreads();
#pragma unroll
    for (int kk = 0; kk < 32; ++kk) {
      const float4 a0 = *(const float4*)&smA[kk * 36 + tr * 8];
      const float4 a1 = *(const float4*)&smA[kk * 36 + tr * 8 + 4];
      const float4 b  = *(const float4*)&smB[kk * 260 + c4];
      float a[8] = {a0.x, a0.y, a0.z, a0.w, a1.x, a1.y, a1.z, a1.w};
#pragma unroll
      for (int r = 0; r < 8; ++r) {
        acc[r][0] = fmaf(a[r], b.x, acc[r][0]);
        acc[r][1] = fmaf(a[r], b.y, acc[r][1]);
        acc[r][2] = fmaf(a[r], b.z, acc[r][2]);
        acc[r][3] = fmaf(a[r], b.w, acc[r][3]);
      }
    }
  }
  const float4 bias = *(const float4*)&enc_b[c4];
  const float4 gv   = *(const float4*)&enc_g[c4];
  const float4 bv   = *(const float4*)&enc_bb[c4];
#pragma unroll
  for (int r = 0; r < 8; ++r) {
    float v0 = acc[r][0] + bias.x, v1 = acc[r][1] + bias.y;
    float v2 = acc[r][2] + bias.z, v3 = acc[r][3] + bias.w;
    float s  = wave_sum64(v0 + v1 + v2 + v3);
    float sq = wave_sum64(v0*v0 + v1*v1 + v2*v2 + v3*v3);
    float mu = s * (1.f / 256.f);
    float rs = rsqrtf(sq * (1.f / 256.f) - mu * mu + 1e-5f);
    float4 o;
    o.x = fmaxf((v0 - mu) * rs * gv.x + bv.x, 0.f);
    o.y = fmaxf((v1 - mu) * rs * gv.y + bv.y, 0.f);
    o.z = fmaxf((v2 - mu) * rs * gv.z + bv.z, 0.f);
    o.w = fmaxf((v3 - mu) * rs * gv.w + bv.w, 0.f);
    const int row = row0 + tr * 8 + r;
    *(float4*)&s1[(size_t)row * FC + c4] = o;
  }
}

// ---------------- Kernel 2: UV[:,0:256]=s1@core_w[0:256], UV[:,256:512]=s1@core_w[256:512] ----------------
__global__ __launch_bounds__(256) void k_uv(
    const float* __restrict__ s1, const float* __restrict__ core_w,
    float* __restrict__ UV)
{
  __shared__ float smA[32 * 36];
  __shared__ float smB[32 * 260];
  const int tid = threadIdx.x;
  const int tr = tid >> 6;
  const int tc = tid & 63;
  const int row0 = blockIdx.x * 32;
  const int y = blockIdx.y;                  // 0 = U (fs half), 1 = V (cs half)
  const float* __restrict__ Bsrc = core_w + (size_t)y * 256 * FC;
  const int c4 = tc * 4;
  float acc[8][4];
#pragma unroll
  for (int r = 0; r < 8; ++r) { acc[r][0]=acc[r][1]=acc[r][2]=acc[r][3]=0.f; }
  const int ka = tid & 31, ra = tid >> 5;
  const int kb = tid >> 6;
  for (int kc = 0; kc < 8; ++kc) {
    const int k0 = kc * 32;
    __syncthreads();
#pragma unroll
    for (int i = 0; i < 4; ++i) {
      int r = ra + i * 8;
      smA[ka * 36 + r] = s1[(size_t)(row0 + r) * FC + k0 + ka];
    }
#pragma unroll
    for (int i = 0; i < 8; ++i) {
      int kk = kb + i * 4;
      *(float4*)&smB[kk * 260 + c4] = *(const float4*)&Bsrc[(size_t)(k0 + kk) * FC + c4];
    }
    __syncthreads();
#pragma unroll
    for (int kk = 0; kk < 32; ++kk) {
      const float4 a0 = *(const float4*)&smA[kk * 36 + tr * 8];
      const float4 a1 = *(const float4*)&smA[kk * 36 + tr * 8 + 4];
      const float4 b  = *(const float4*)&smB[kk * 260 + c4];
      float a[8] = {a0.x, a0.y, a0.z, a0.w, a1.x, a1.y, a1.z, a1.w};
#pragma unroll
      for (int r = 0; r < 8; ++r) {
        acc[r][0] = fmaf(a[r], b.x, acc[r][0]);
        acc[r][1] = fmaf(a[r], b.y, acc[r][1]);
        acc[r][2] = fmaf(a[r], b.z, acc[r][2]);
        acc[r][3] = fmaf(a[r], b.w, acc[r][3]);
      }
    }
  }
#pragma unroll
  for (int r = 0; r < 8; ++r) {
    const int row = row0 + tr * 8 + r;
    float4 o = make_float4(acc[r][0], acc[r][1], acc[r][2], acc[r][3]);
    *(float4*)&UV[(size_t)row * 512 + y * 256 + c4] = o;
  }
}

// Build the 56 core rows of group g into smA (bf16, [c 0..255][row 0..63], stride 72)
__device__ __forceinline__ void build_core(
    const float* __restrict__ UV, const float* __restrict__ core_b,
    const float* __restrict__ core_g, const float* __restrict__ core_bb,
    int g, int tid, unsigned short* smA)
{
  const int wv = tid >> 6;   // wave 0..3
  const int l  = tid & 63;
  for (int p = wv; p < 56; p += 4) {
    const int i = p / 7, t = p - i * 7;
    const int j = t + (t >= i ? 1 : 0);
    const float* uA = UV + (size_t)(g * 8 + i) * 512;
    const float* vB = UV + (size_t)(g * 8 + j) * 512 + 256;
    float v[4];
    float s = 0.f, sq = 0.f;
#pragma unroll
    for (int q = 0; q < 4; ++q) {
      const int c = q * 64 + l;
      float val = uA[c] + vB[c] + core_b[c];
      v[q] = val; s += val; sq += val * val;
    }
    s  = wave_sum64(s);
    sq = wave_sum64(sq);
    const float mu = s * (1.f / 256.f);
    const float rs = rsqrtf(sq * (1.f / 256.f) - mu * mu + 1e-5f);
#pragma unroll
    for (int q = 0; q < 4; ++q) {
      const int c = q * 64 + l;
      float o = fmaxf((v[q] - mu) * rs * core_g[c] + core_bb[c], 0.f);
      unsigned ub = __float_as_uint(o) + 0x8000u;  // round to nearest bf16
      smA[c * 72 + p] = (unsigned short)(ub >> 16);
    }
  }
  // zero pad rows 56..63
#pragma unroll
  for (int r = 56; r < 64; ++r) smA[tid * 72 + r] = 0;
}

// ---------------- Kernel 3a: att = sigmoid(tanh(LN(core@att1_w+b)) @ att2_w + b2) ----------------
__global__ __launch_bounds__(256) void k_att(
    const float* __restrict__ UV, const float* __restrict__ core_b,
    const float* __restrict__ core_g, const float* __restrict__ core_bb,
    const float* __restrict__ att1_w, const float* __restrict__ att1_b,
    const float* __restrict__ att_g, const float* __restrict__ att_bb,
    const float* __restrict__ att2_w, const float* __restrict__ att2_b,
    float* __restrict__ att)
{
  __shared__ unsigned short smA[256 * 72];  // core^T bf16
  __shared__ float smB[32 * 132];
  const int g = blockIdx.x;
  const int tid = threadIdx.x;
  build_core(UV, core_b, core_g, core_bb, g, tid, smA);

  const int tr = tid >> 5;        // 0..7 -> rows tr*8
  const int tc = tid & 31;        // cols tc*4 (0..127)
  const int c4 = tc * 4;
  float acc[8][4];
#pragma unroll
  for (int r = 0; r < 8; ++r) { acc[r][0]=acc[r][1]=acc[r][2]=acc[r][3]=0.f; }
  const int cb4 = (tid & 31) * 4, kr = tid >> 5;
  for (int kc = 0; kc < 8; ++kc) {
    const int k0 = kc * 32;
    __syncthreads();
#pragma unroll
    for (int i = 0; i < 4; ++i) {
      int kk = kr + i * 8;
      *(float4*)&smB[kk * 132 + cb4] = *(const float4*)&att1_w[(size_t)(k0 + kk) * LASTN + cb4];
    }
    __syncthreads();
#pragma unroll
    for (int kk = 0; kk < 32; ++kk) {
      const int k = k0 + kk;
      uint4 au = *(const uint4*)&smA[k * 72 + tr * 8];
      float a[8]; unpack8(au, a);
      const float4 b = *(const float4*)&smB[kk * 132 + c4];
#pragma unroll
      for (int r = 0; r < 8; ++r) {
        acc[r][0] = fmaf(a[r], b.x, acc[r][0]);
        acc[r][1] = fmaf(a[r], b.y, acc[r][1]);
        acc[r][2] = fmaf(a[r], b.z, acc[r][2]);
        acc[r][3] = fmaf(a[r], b.w, acc[r][3]);
      }
    }
  }
  const float4 bias = *(const float4*)&att1_b[c4];
  const float4 gv   = *(const float4*)&att_g[c4];
  const float4 bv   = *(const float4*)&att_bb[c4];
  const float4 w2   = *(const float4*)&att2_w[c4];
  const float  b2   = att2_b[0];
#pragma unroll
  for (int r = 0; r < 8; ++r) {
    float v0 = acc[r][0] + bias.x, v1 = acc[r][1] + bias.y;
    float v2 = acc[r][2] + bias.z, v3 = acc[r][3] + bias.w;
    float s  = wave_sum32(v0 + v1 + v2 + v3);
    float sq = wave_sum32(v0*v0 + v1*v1 + v2*v2 + v3*v3);
    float mu = s * (1.f / 128.f);
    float rs = rsqrtf(sq * (1.f / 128.f) - mu * mu + 1e-5f);
    float h0 = tanhf((v0 - mu) * rs * gv.x + bv.x);
    float h1 = tanhf((v1 - mu) * rs * gv.y + bv.y);
    float h2 = tanhf((v2 - mu) * rs * gv.z + bv.z);
    float h3 = tanhf((v3 - mu) * rs * gv.w + bv.w);
    float d = wave_sum32(h0 * w2.x + h1 * w2.y + h2 * w2.z + h3 * w2.w);
    if (tc == 0) {
      const int prow = tr * 8 + r;
      if (prow < 56) att[(size_t)g * 56 + prow] = 1.f / (1.f + expf(-(d + b2)));
    }
  }
}

// ---------------- Kernel 3b: effect = sum_t relu(LN(core@ctx_w+b)) * att ----------------
__global__ __launch_bounds__(256) void k_ctx(
    const float* __restrict__ UV, const float* __restrict__ core_b,
    const float* __restrict__ core_g, const float* __restrict__ core_bb,
    const float* __restrict__ ctx_w, const float* __restrict__ ctx_b,
    const float* __restrict__ ctx_g, const float* __restrict__ ctx_bb,
    const float* __restrict__ att, float* __restrict__ effect)
{
  __shared__ float smem[15040];   // 60160 B: [bf16 core 36864B][smB 16640B] / epi: 56*260 f32
  unsigned short* smA = (unsigned short*)smem;
  float* smB = smem + 9216;
  const int g = blockIdx.x;
  const int tid = threadIdx.x;
  build_core(UV, core_b, core_g, core_bb, g, tid, smA);

  const int tr = tid >> 6;        // 0..3 -> rows tr*16
  const int tc = tid & 63;        // cols tc*4
  const int c4 = tc * 4;
  float acc[16][4];
#pragma unroll
  for (int r = 0; r < 16; ++r) { acc[r][0]=acc[r][1]=acc[r][2]=acc[r][3]=0.f; }
  const int kr = tid >> 6;
  for (int kc = 0; kc < 16; ++kc) {    // Kt = 16
    __syncthreads();
#pragma unroll
    for (int i = 0; i < 4; ++i) {
      int kk = kr + i * 4;
      *(float4*)&smB[kk * 260 + c4] = *(const float4*)&ctx_w[(size_t)(kc * 16 + kk) * FC + c4];
    }
    __syncthreads();
#pragma unroll
    for (int kk = 0; kk < 16; ++kk) {
      const int k = kc * 16 + kk;
      uint4 au0 = *(const uint4*)&smA[k * 72 + tr * 16];
      uint4 au1 = *(const uint4*)&smA[k * 72 + tr * 16 + 8];
      float a[16]; unpack8(au0, a); unpack8(au1, a + 8);
      const float4 b = *(const float4*)&smB[kk * 260 + c4];
#pragma unroll
      for (int r = 0; r < 16; ++r) {
        acc[r][0] = fmaf(a[r], b.x, acc[r][0]);
        acc[r][1] = fmaf(a[r], b.y, acc[r][1]);
        acc[r][2] = fmaf(a[r], b.z, acc[r][2]);
        acc[r][3] = fmaf(a[r], b.w, acc[r][3]);
      }
    }
  }
  __syncthreads();   // GEMM reads done; smem may be reused
  float* smS = smem; // [56][260] scaled ctx
  const float4 bias = *(const float4*)&ctx_b[c4];
  const float4 gv   = *(const float4*)&ctx_g[c4];
  const float4 bv   = *(const float4*)&ctx_bb[c4];
#pragma unroll
  for (int r = 0; r < 16; ++r) {
    const int prow = tr * 16 + r;
    float v0 = acc[r][0] + bias.x, v1 = acc[r][1] + bias.y;
    float v2 = acc[r][2] + bias.z, v3 = acc[r][3] + bias.w;
    float s  = wave_sum64(v0 + v1 + v2 + v3);
    float sq = wave_sum64(v0*v0 + v1*v1 + v2*v2 + v3*v3);
    float mu = s * (1.f / 256.f);
    float rs = rsqrtf(sq * (1.f / 256.f) - mu * mu + 1e-5f);
    float ap = (prow < 56) ? att[(size_t)g * 56 + prow] : 0.f;
    float o0 = fmaxf((v0 - mu) * rs * gv.x + bv.x, 0.f) * ap;
    float o1 = fmaxf((v1 - mu) * rs * gv.y + bv.y, 0.f) * ap;
    float o2 = fmaxf((v2 - mu) * rs * gv.z + bv.z, 0.f) * ap;
    float o3 = fmaxf((v3 - mu) * rs * gv.w + bv.w, 0.f) * ap;
    if (prow < 56) {
      *(float4*)&smS[prow * 260 + c4] = make_float4(o0, o1, o2, o3);
    }
  }
  __syncthreads();
  const int c = tid;  // 0..255
#pragma unroll
  for (int i = 0; i < 8; ++i) {
    float s = 0.f;
#pragma unroll
    for (int t2 = 0; t2 < 7; ++t2) s += smS[(i * 7 + t2) * 260 + c];
    effect[(size_t)(g * 8 + i) * FC + c] = s;
  }
}

// ---------------- Kernel 4: out = [s1|effect|x] @ out_w + out_b (written twice) ----------------
__global__ __launch_bounds__(256) void k_out(
    const float* __restrict__ s1, const float* __restrict__ effect,
    const float* __restrict__ x, const float* __restrict__ out_w,
    const float* __restrict__ out_b, float* __restrict__ out, int dup)
{
  __shared__ float smA[32 * 36];
  __shared__ float smB[32 * 260];
  const int tid = threadIdx.x;
  const int tr = tid >> 6;
  const int tc = tid & 63;
  const int row0 = blockIdx.x * 32;
  const int c4 = tc * 4;
  float acc[8][4];
#pragma unroll
  for (int r = 0; r < 8; ++r) { acc[r][0]=acc[r][1]=acc[r][2]=acc[r][3]=0.f; }
  const int ka = tid & 31, ra = tid >> 5;
  const int kb = tid >> 6;
  for (int kc = 0; kc < 48; ++kc) {
    const int k0 = kc * 32;
    const float* src; int ld, koff;
    if (k0 < 256)      { src = s1;     ld = 256;  koff = k0; }
    else if (k0 < 512) { src = effect; ld = 256;  koff = k0 - 256; }
    else               { src = x;      ld = 1024; koff = k0 - 512; }
    __syncthreads();
#pragma unroll
    for (int i = 0; i < 4; ++i) {
      int r = ra + i * 8;
      smA[ka * 36 + r] = src[(size_t)(row0 + r) * ld + koff + ka];
    }
#pragma unroll
    for (int i = 0; i < 8; ++i) {
      int kk = kb + i * 4;
      *(float4*)&smB[kk * 260 + c4] = *(const float4*)&out_w[(size_t)(k0 + kk) * FC + c4];
    }
    __syncthreads();
#pragma unroll
    for (int kk = 0; kk < 32; ++kk) {
      const float4 a0 = *(const float4*)&smA[kk * 36 + tr * 8];
      const float4 a1 = *(const float4*)&smA[kk * 36 + tr * 8 + 4];
      const float4 b  = *(const float4*)&smB[kk * 260 + c4];
      float a[8] = {a0.x, a0.y, a0.z, a0.w, a1.x, a1.y, a1.z, a1.w};
#pragma unroll
      for (int r = 0; r < 8; ++r) {
        acc[r][0] = fmaf(a[r], b.x, acc[r][0]);
        acc[r][1] = fmaf(a[r], b.y, acc[r][1]);
        acc[r][2] = fmaf(a[r], b.z, acc[r][2]);
        acc[r][3] = fmaf(a[r], b.w, acc[r][3]);
      }
    }
  }
  const float4 ob = *(const float4*)&out_b[c4];
#pragma unroll
  for (int r = 0; r < 8; ++r) {
    const int row = row0 + tr * 8 + r;
    float4 o = make_float4(acc[r][0] + ob.x, acc[r][1] + ob.y,
                           acc[r][2] + ob.z, acc[r][3] + ob.w);
    *(float4*)&out[(size_t)row * FC + c4] = o;
    if (dup) *(float4*)&out[(size_t)NROW * FC + (size_t)row * FC + c4] = o;
  }
}

extern "C" void kernel_launch(void* const* d_in, const int* in_sizes, int n_in,
                              void* d_out, int out_size, void* d_ws, size_t ws_size,
                              hipStream_t stream) {
  const float* x      = (const float*)d_in[0];
  const float* state  = (const float*)d_in[1];
  const float* enc_w  = (const float*)d_in[2];
  const float* enc_b  = (const float*)d_in[3];
  const float* enc_g  = (const float*)d_in[4];
  const float* enc_bb = (const float*)d_in[5];
  const float* core_w = (const float*)d_in[6];
  const float* core_b = (const float*)d_in[7];
  const float* core_g = (const float*)d_in[8];
  const float* core_bb= (const float*)d_in[9];
  const float* ctx_w  = (const float*)d_in[10];
  const float* ctx_b  = (const float*)d_in[11];
  const float* ctx_g  = (const float*)d_in[12];
  const float* ctx_bb = (const float*)d_in[13];
  const float* att1_w = (const float*)d_in[14];
  const float* att1_b = (const float*)d_in[15];
  const float* att_g  = (const float*)d_in[16];
  const float* att_bb = (const float*)d_in[17];
  const float* att2_w = (const float*)d_in[18];
  const float* att2_b = (const float*)d_in[19];
  const float* out_w  = (const float*)d_in[20];
  const float* out_b  = (const float*)d_in[21];

  float* ws = (float*)d_ws;
  float* s1     = ws;                       // 16384*256   = 4,194,304 floats
  float* UV     = ws + 4194304;             // 16384*512   = 8,388,608
  float* att    = ws + 12582912;            // 114,688
  float* effect = ws + 12697600;            // 4,194,304
  float* out    = (float*)d_out;
  const int dup = (out_size >= 2 * NROW * FC) ? 1 : 0;

  k_enc<<<dim3(NROW / 32), 256, 0, stream>>>(state, enc_w, enc_b, enc_g, enc_bb, s1);
  k_uv <<<dim3(NROW / 32, 2), 256, 0, stream>>>(s1, core_w, UV);
  k_att<<<dim3(NGRP), 256, 0, stream>>>(UV, core_b, core_g, core_bb,
                                        att1_w, att1_b, att_g, att_bb,
                                        att2_w, att2_b, att);
  k_ctx<<<dim3(NGRP), 256, 0, stream>>>(UV, core_b, core_g, core_bb,
                                        ctx_w, ctx_b, ctx_g, ctx_bb,
                                        att, effect);
  k_out<<<dim3(NROW / 32), 256, 0, stream>>>(s1, effect, x, out_w, out_b, out, dup);
}

// Round 2
// 778.688 us; speedup vs baseline: 1.2702x; 1.2702x over previous
//
#include <hip/hip_runtime.h>
#include <stdint.h>

#define FC    256
#define HH    512
#define MX    1024
#define LASTN 128
#define NROW  16384
#define NGRP  2048

typedef __bf16 bf16x8 __attribute__((ext_vector_type(8)));
typedef float  f32x4  __attribute__((ext_vector_type(4)));

__device__ __forceinline__ float wave_sum64(float v) {
#pragma unroll
  for (int m = 1; m < 64; m <<= 1) v += __shfl_xor(v, m);
  return v;
}
__device__ __forceinline__ float red16(float v) {
#pragma unroll
  for (int m = 1; m < 16; m <<= 1) v += __shfl_xor(v, m);
  return v;
}
__device__ __forceinline__ unsigned short to_bf16(float f) {
  unsigned u = __float_as_uint(f);
  return (unsigned short)((u + 0x8000u) >> 16);
}
__device__ __forceinline__ float from_bf16(unsigned short s) {
  return __uint_as_float(((unsigned)s) << 16);
}

// ---------------- Kernel 1: s1 = relu(LN(state @ enc_w + enc_b)) ----------------
__global__ __launch_bounds__(256) void k_enc(
    const float* __restrict__ state, const float* __restrict__ enc_w,
    const float* __restrict__ enc_b, const float* __restrict__ enc_g,
    const float* __restrict__ enc_bb, float* __restrict__ s1)
{
  __shared__ float smA[32 * 36];
  __shared__ float smB[32 * 260];
  const int tid = threadIdx.x;
  const int tr = tid >> 6;
  const int tc = tid & 63;
  const int row0 = blockIdx.x * 32;
  const int c4 = tc * 4;
  float acc[8][4];
#pragma unroll
  for (int r = 0; r < 8; ++r) { acc[r][0]=acc[r][1]=acc[r][2]=acc[r][3]=0.f; }
  const int ka = tid & 31, ra = tid >> 5;
  const int kb = tid >> 6;
  for (int kc = 0; kc < 16; ++kc) {
    const int k0 = kc * 32;
    __syncthreads();
#pragma unroll
    for (int i = 0; i < 4; ++i) {
      int r = ra + i * 8;
      smA[ka * 36 + r] = state[(size_t)(row0 + r) * HH + k0 + ka];
    }
#pragma unroll
    for (int i = 0; i < 8; ++i) {
      int kk = kb + i * 4;
      *(float4*)&smB[kk * 260 + c4] = *(const float4*)&enc_w[(size_t)(k0 + kk) * FC + c4];
    }
    __syncthreads();
#pragma unroll
    for (int kk = 0; kk < 32; ++kk) {
      const float4 a0 = *(const float4*)&smA[kk * 36 + tr * 8];
      const float4 a1 = *(const float4*)&smA[kk * 36 + tr * 8 + 4];
      const float4 b  = *(const float4*)&smB[kk * 260 + c4];
      float a[8] = {a0.x, a0.y, a0.z, a0.w, a1.x, a1.y, a1.z, a1.w};
#pragma unroll
      for (int r = 0; r < 8; ++r) {
        acc[r][0] = fmaf(a[r], b.x, acc[r][0]);
        acc[r][1] = fmaf(a[r], b.y, acc[r][1]);
        acc[r][2] = fmaf(a[r], b.z, acc[r][2]);
        acc[r][3] = fmaf(a[r], b.w, acc[r][3]);
      }
    }
  }
  const float4 bias = *(const float4*)&enc_b[c4];
  const float4 gv   = *(const float4*)&enc_g[c4];
  const float4 bv   = *(const float4*)&enc_bb[c4];
#pragma unroll
  for (int r = 0; r < 8; ++r) {
    float v0 = acc[r][0] + bias.x, v1 = acc[r][1] + bias.y;
    float v2 = acc[r][2] + bias.z, v3 = acc[r][3] + bias.w;
    float s  = wave_sum64(v0 + v1 + v2 + v3);
    float sq = wave_sum64(v0*v0 + v1*v1 + v2*v2 + v3*v3);
    float mu = s * (1.f / 256.f);
    float rs = rsqrtf(sq * (1.f / 256.f) - mu * mu + 1e-5f);
    float4 o;
    o.x = fmaxf((v0 - mu) * rs * gv.x + bv.x, 0.f);
    o.y = fmaxf((v1 - mu) * rs * gv.y + bv.y, 0.f);
    o.z = fmaxf((v2 - mu) * rs * gv.z + bv.z, 0.f);
    o.w = fmaxf((v3 - mu) * rs * gv.w + bv.w, 0.f);
    const int row = row0 + tr * 8 + r;
    *(float4*)&s1[(size_t)row * FC + c4] = o;
  }
}

// ---------------- Kernel 2: UV = s1 @ core_w (both halves) ----------------
__global__ __launch_bounds__(256) void k_uv(
    const float* __restrict__ s1, const float* __restrict__ core_w,
    float* __restrict__ UV)
{
  __shared__ float smA[32 * 36];
  __shared__ float smB[32 * 260];
  const int tid = threadIdx.x;
  const int tr = tid >> 6;
  const int tc = tid & 63;
  const int row0 = blockIdx.x * 32;
  const int y = blockIdx.y;
  const float* __restrict__ Bsrc = core_w + (size_t)y * 256 * FC;
  const int c4 = tc * 4;
  float acc[8][4];
#pragma unroll
  for (int r = 0; r < 8; ++r) { acc[r][0]=acc[r][1]=acc[r][2]=acc[r][3]=0.f; }
  const int ka = tid & 31, ra = tid >> 5;
  const int kb = tid >> 6;
  for (int kc = 0; kc < 8; ++kc) {
    const int k0 = kc * 32;
    __syncthreads();
#pragma unroll
    for (int i = 0; i < 4; ++i) {
      int r = ra + i * 8;
      smA[ka * 36 + r] = s1[(size_t)(row0 + r) * FC + k0 + ka];
    }
#pragma unroll
    for (int i = 0; i < 8; ++i) {
      int kk = kb + i * 4;
      *(float4*)&smB[kk * 260 + c4] = *(const float4*)&Bsrc[(size_t)(k0 + kk) * FC + c4];
    }
    __syncthreads();
#pragma unroll
    for (int kk = 0; kk < 32; ++kk) {
      const float4 a0 = *(const float4*)&smA[kk * 36 + tr * 8];
      const float4 a1 = *(const float4*)&smA[kk * 36 + tr * 8 + 4];
      const float4 b  = *(const float4*)&smB[kk * 260 + c4];
      float a[8] = {a0.x, a0.y, a0.z, a0.w, a1.x, a1.y, a1.z, a1.w};
#pragma unroll
      for (int r = 0; r < 8; ++r) {
        acc[r][0] = fmaf(a[r], b.x, acc[r][0]);
        acc[r][1] = fmaf(a[r], b.y, acc[r][1]);
        acc[r][2] = fmaf(a[r], b.z, acc[r][2]);
        acc[r][3] = fmaf(a[r], b.w, acc[r][3]);
      }
    }
  }
#pragma unroll
  for (int r = 0; r < 8; ++r) {
    const int row = row0 + tr * 8 + r;
    float4 o = make_float4(acc[r][0], acc[r][1], acc[r][2], acc[r][3]);
    *(float4*)&UV[(size_t)row * 512 + y * 256 + c4] = o;
  }
}

// ---------------- Prep: transpose weights to bf16 Wt[n][k] ----------------
__global__ __launch_bounds__(256) void k_prep(
    const float* __restrict__ ctx_w, const float* __restrict__ att1_w,
    unsigned short* __restrict__ ctxT, unsigned short* __restrict__ att1T)
{
  const int idx = blockIdx.x * 256 + threadIdx.x;   // 0..65535
  {
    const int n = idx >> 8, k = idx & 255;
    ctxT[idx] = to_bf16(ctx_w[(size_t)k * FC + n]);
  }
  if (idx < 32768) {
    const int n = idx >> 8, k = idx & 255;
    att1T[idx] = to_bf16(att1_w[(size_t)k * LASTN + n]);
  }
}

// Build core rows of group g in row-major bf16: smA[p*264 + c], rows 56..63 zeroed
__device__ __forceinline__ void build_core_rm(
    const float* __restrict__ UV, const float* __restrict__ core_b,
    const float* __restrict__ core_g, const float* __restrict__ core_bb,
    int g, int tid, unsigned short* smA)
{
  const int wv = tid >> 6;
  const int l  = tid & 63;
  for (int p = wv; p < 56; p += 4) {
    const int i = p / 7, t = p - i * 7;
    const int j = t + (t >= i ? 1 : 0);
    const float* uA = UV + (size_t)(g * 8 + i) * 512;
    const float* vB = UV + (size_t)(g * 8 + j) * 512 + 256;
    float v[4];
    float s = 0.f, sq = 0.f;
#pragma unroll
    for (int q = 0; q < 4; ++q) {
      const int c = q * 64 + l;
      float val = uA[c] + vB[c] + core_b[c];
      v[q] = val; s += val; sq += val * val;
    }
    s  = wave_sum64(s);
    sq = wave_sum64(sq);
    const float mu = s * (1.f / 256.f);
    const float rs = rsqrtf(sq * (1.f / 256.f) - mu * mu + 1e-5f);
#pragma unroll
    for (int q = 0; q < 4; ++q) {
      const int c = q * 64 + l;
      float o = fmaxf((v[q] - mu) * rs * core_g[c] + core_bb[c], 0.f);
      smA[p * 264 + c] = to_bf16(o);
    }
  }
  for (int idx = tid; idx < 8 * 264; idx += 256) smA[56 * 264 + idx] = 0;
}

// ---------------- Fused k_att + k_ctx with MFMA ----------------
// Per group: core (64x256 bf16, rows 56..63 zero) -> GEMM vs ctxT (256x256) and
// att1T (128x256); att epilogue in-register; ctx epilogue scaled by att; effect out.
__global__ __launch_bounds__(256) void k_pair(
    const float* __restrict__ UV, const float* __restrict__ core_b,
    const float* __restrict__ core_g, const float* __restrict__ core_bb,
    const unsigned short* __restrict__ ctxT, const float* __restrict__ ctx_b,
    const float* __restrict__ ctx_g, const float* __restrict__ ctx_bb,
    const unsigned short* __restrict__ att1T, const float* __restrict__ att1_b,
    const float* __restrict__ att_g, const float* __restrict__ att_bb,
    const float* __restrict__ att2_w, const float* __restrict__ att2_b,
    float* __restrict__ effect)
{
  __shared__ unsigned short smA[64 * 264];   // 33792 B: core bf16, later reused for scaled ctx
  __shared__ float att_s[64];
  const int g = blockIdx.x;
  const int tid = threadIdx.x;
  build_core_rm(UV, core_b, core_g, core_bb, g, tid, smA);
  __syncthreads();

  const int lane = tid & 63;
  const int wv   = tid >> 6;          // wave -> rows 16*wv .. 16*wv+15
  const int cl   = lane & 15;
  const int quad = lane >> 4;

  f32x4 accC[16];
  f32x4 accT[8];
#pragma unroll
  for (int t = 0; t < 16; ++t) accC[t] = (f32x4){0.f, 0.f, 0.f, 0.f};
#pragma unroll
  for (int t = 0; t < 8; ++t)  accT[t] = (f32x4){0.f, 0.f, 0.f, 0.f};

  const unsigned short* aRow = smA + (wv * 16 + cl) * 264 + quad * 8;
  for (int kc = 0; kc < 8; ++kc) {
    const int k0 = kc * 32 + quad * 8;
    bf16x8 af;
    {
      uint4 u = *(const uint4*)(aRow + kc * 32);
      af = __builtin_bit_cast(bf16x8, u);
    }
#pragma unroll
    for (int t = 0; t < 16; ++t) {
      bf16x8 bf = *(const bf16x8*)(ctxT + (size_t)(t * 16 + cl) * 256 + k0);
      accC[t] = __builtin_amdgcn_mfma_f32_16x16x32_bf16(af, bf, accC[t], 0, 0, 0);
    }
#pragma unroll
    for (int t = 0; t < 8; ++t) {
      bf16x8 bf = *(const bf16x8*)(att1T + (size_t)(t * 16 + cl) * 256 + k0);
      accT[t] = __builtin_amdgcn_mfma_f32_16x16x32_bf16(af, bf, accT[t], 0, 0, 0);
    }
  }

  // ---- att epilogue: LN over 128 cols -> tanh -> dot att2_w -> sigmoid ----
  const float b2 = att2_b[0];
#pragma unroll
  for (int r4 = 0; r4 < 4; ++r4) {
    float v[8], s = 0.f, sq = 0.f;
#pragma unroll
    for (int t = 0; t < 8; ++t) {
      const int col = t * 16 + cl;
      v[t] = accT[t][r4] + att1_b[col];
      s += v[t]; sq += v[t] * v[t];
    }
    s = red16(s); sq = red16(sq);
    const float mu = s * (1.f / 128.f);
    const float rs = rsqrtf(sq * (1.f / 128.f) - mu * mu + 1e-5f);
    float d = 0.f;
#pragma unroll
    for (int t = 0; t < 8; ++t) {
      const int col = t * 16 + cl;
      float h = tanhf((v[t] - mu) * rs * att_g[col] + att_bb[col]);
      d = fmaf(h, att2_w[col], d);
    }
    d = red16(d);
    if (cl == 0) {
      const int r = wv * 16 + quad * 4 + r4;
      att_s[r] = 1.f / (1.f + expf(-(d + b2)));
    }
  }
  __syncthreads();   // all GEMM LDS reads done + att_s visible

  // ---- ctx epilogue: LN over 256 cols -> relu -> * att -> bf16 into LDS ----
  unsigned short* smS = smA;   // reuse, stride 264
#pragma unroll
  for (int r4 = 0; r4 < 4; ++r4) {
    float v[16], s = 0.f, sq = 0.f;
#pragma unroll
    for (int t = 0; t < 16; ++t) {
      const int col = t * 16 + cl;
      v[t] = accC[t][r4] + ctx_b[col];
      s += v[t]; sq += v[t] * v[t];
    }
    s = red16(s); sq = red16(sq);
    const float mu = s * (1.f / 256.f);
    const float rs = rsqrtf(sq * (1.f / 256.f) - mu * mu + 1e-5f);
    const int r = wv * 16 + quad * 4 + r4;
    const float ap = (r < 56) ? att_s[r] : 0.f;
    if (r < 56) {
#pragma unroll
      for (int t = 0; t < 16; ++t) {
        const int col = t * 16 + cl;
        float o = fmaxf((v[t] - mu) * rs * ctx_g[col] + ctx_bb[col], 0.f) * ap;
        smS[r * 264 + col] = to_bf16(o);
      }
    }
  }
  __syncthreads();

  // ---- effect[i][c] = sum over 7 partners ----
  const int c = tid;
#pragma unroll
  for (int i = 0; i < 8; ++i) {
    float s = 0.f;
#pragma unroll
    for (int t2 = 0; t2 < 7; ++t2) s += from_bf16(smS[(i * 7 + t2) * 264 + c]);
    effect[(size_t)(g * 8 + i) * FC + c] = s;
  }
}

// ---------------- Kernel 4: out = [s1|effect|x] @ out_w + out_b ----------------
__global__ __launch_bounds__(256) void k_out(
    const float* __restrict__ s1, const float* __restrict__ effect,
    const float* __restrict__ x, const float* __restrict__ out_w,
    const float* __restrict__ out_b, float* __restrict__ out, int dup)
{
  __shared__ float smA[32 * 36];
  __shared__ float smB[32 * 260];
  const int tid = threadIdx.x;
  const int tr = tid >> 6;
  const int tc = tid & 63;
  const int row0 = blockIdx.x * 32;
  const int c4 = tc * 4;
  float acc[8][4];
#pragma unroll
  for (int r = 0; r < 8; ++r) { acc[r][0]=acc[r][1]=acc[r][2]=acc[r][3]=0.f; }
  const int ka = tid & 31, ra = tid >> 5;
  const int kb = tid >> 6;
  for (int kc = 0; kc < 48; ++kc) {
    const int k0 = kc * 32;
    const float* src; int ld, koff;
    if (k0 < 256)      { src = s1;     ld = 256;  koff = k0; }
    else if (k0 < 512) { src = effect; ld = 256;  koff = k0 - 256; }
    else               { src = x;      ld = 1024; koff = k0 - 512; }
    __syncthreads();
#pragma unroll
    for (int i = 0; i < 4; ++i) {
      int r = ra + i * 8;
      smA[ka * 36 + r] = src[(size_t)(row0 + r) * ld + koff + ka];
    }
#pragma unroll
    for (int i = 0; i < 8; ++i) {
      int kk = kb + i * 4;
      *(float4*)&smB[kk * 260 + c4] = *(const float4*)&out_w[(size_t)(k0 + kk) * FC + c4];
    }
    __syncthreads();
#pragma unroll
    for (int kk = 0; kk < 32; ++kk) {
      const float4 a0 = *(const float4*)&smA[kk * 36 + tr * 8];
      const float4 a1 = *(const float4*)&smA[kk * 36 + tr * 8 + 4];
      const float4 b  = *(const float4*)&smB[kk * 260 + c4];
      float a[8] = {a0.x, a0.y, a0.z, a0.w, a1.x, a1.y, a1.z, a1.w};
#pragma unroll
      for (int r = 0; r < 8; ++r) {
        acc[r][0] = fmaf(a[r], b.x, acc[r][0]);
        acc[r][1] = fmaf(a[r], b.y, acc[r][1]);
        acc[r][2] = fmaf(a[r], b.z, acc[r][2]);
        acc[r][3] = fmaf(a[r], b.w, acc[r][3]);
      }
    }
  }
  const float4 ob = *(const float4*)&out_b[c4];
#pragma unroll
  for (int r = 0; r < 8; ++r) {
    const int row = row0 + tr * 8 + r;
    float4 o = make_float4(acc[r][0] + ob.x, acc[r][1] + ob.y,
                           acc[r][2] + ob.z, acc[r][3] + ob.w);
    *(float4*)&out[(size_t)row * FC + c4] = o;
    if (dup) *(float4*)&out[(size_t)NROW * FC + (size_t)row * FC + c4] = o;
  }
}

extern "C" void kernel_launch(void* const* d_in, const int* in_sizes, int n_in,
                              void* d_out, int out_size, void* d_ws, size_t ws_size,
                              hipStream_t stream) {
  const float* x      = (const float*)d_in[0];
  const float* state  = (const float*)d_in[1];
  const float* enc_w  = (const float*)d_in[2];
  const float* enc_b  = (const float*)d_in[3];
  const float* enc_g  = (const float*)d_in[4];
  const float* enc_bb = (const float*)d_in[5];
  const float* core_w = (const float*)d_in[6];
  const float* core_b = (const float*)d_in[7];
  const float* core_g = (const float*)d_in[8];
  const float* core_bb= (const float*)d_in[9];
  const float* ctx_w  = (const float*)d_in[10];
  const float* ctx_b  = (const float*)d_in[11];
  const float* ctx_g  = (const float*)d_in[12];
  const float* ctx_bb = (const float*)d_in[13];
  const float* att1_w = (const float*)d_in[14];
  const float* att1_b = (const float*)d_in[15];
  const float* att_g  = (const float*)d_in[16];
  const float* att_bb = (const float*)d_in[17];
  const float* att2_w = (const float*)d_in[18];
  const float* att2_b = (const float*)d_in[19];
  const float* out_w  = (const float*)d_in[20];
  const float* out_b  = (const float*)d_in[21];

  float* ws = (float*)d_ws;
  float* s1     = ws;                        // 16384*256 = 4,194,304 floats
  float* UV     = ws + 4194304;              // 16384*512 = 8,388,608
  float* effect = ws + 12582912;             // 4,194,304
  unsigned short* ctxT  = (unsigned short*)(ws + 16777216);  // 65536 bf16
  unsigned short* att1T = ctxT + 65536;                      // 32768 bf16
  float* out    = (float*)d_out;
  const int dup = (out_size >= 2 * NROW * FC) ? 1 : 0;

  k_prep<<<dim3(256), 256, 0, stream>>>(ctx_w, att1_w, ctxT, att1T);
  k_enc<<<dim3(NROW / 32), 256, 0, stream>>>(state, enc_w, enc_b, enc_g, enc_bb, s1);
  k_uv <<<dim3(NROW / 32, 2), 256, 0, stream>>>(s1, core_w, UV);
  k_pair<<<dim3(NGRP), 256, 0, stream>>>(UV, core_b, core_g, core_bb,
                                         ctxT, ctx_b, ctx_g, ctx_bb,
                                         att1T, att1_b, att_g, att_bb,
                                         att2_w, att2_b, effect);
  k_out<<<dim3(NROW / 32), 256, 0, stream>>>(s1, effect, x, out_w, out_b, out, dup);
}

// Round 3
// 361.687 us; speedup vs baseline: 2.7346x; 2.1529x over previous
//
#include <hip/hip_runtime.h>
#include <stdint.h>

#define FC    256
#define HH    512
#define MX    1024
#define LASTN 128
#define NROW  16384
#define NGRP  2048

typedef unsigned short u16;
typedef __bf16 bf16x8 __attribute__((ext_vector_type(8)));
typedef float  f32x4  __attribute__((ext_vector_type(4)));

__device__ __forceinline__ float wave_sum64(float v) {
#pragma unroll
  for (int m = 1; m < 64; m <<= 1) v += __shfl_xor(v, m);
  return v;
}
__device__ __forceinline__ float red16(float v) {
#pragma unroll
  for (int m = 1; m < 16; m <<= 1) v += __shfl_xor(v, m);
  return v;
}
__device__ __forceinline__ u16 to_bf16(float f) {
  unsigned u = __float_as_uint(f);
  return (u16)((u + 0x8000u) >> 16);
}
__device__ __forceinline__ float from_bf16(u16 s) {
  return __uint_as_float(((unsigned)s) << 16);
}
__device__ __forceinline__ uint32_t pk2(float a, float b) {
  return (uint32_t)to_bf16(a) | ((uint32_t)to_bf16(b) << 16);
}
// async global->LDS, 16B per lane; LDS dest = wave-uniform base + lane*16
__device__ __forceinline__ void glds16(const void* g, void* l) {
  __builtin_amdgcn_global_load_lds(
      (__attribute__((address_space(1))) uint32_t*)g,
      (__attribute__((address_space(3))) uint32_t*)l, 16, 0, 0);
}
__device__ __forceinline__ bf16x8 frag_ld(const u16* p) {
  return __builtin_bit_cast(bf16x8, *(const uint4*)p);
}

// ============ k_prep: weights -> fragment-ordered bf16 global layout ============
// unit id = (u*NKC + kc)*64 + l ; contents j=0..7: W[kc*32+(l>>4)*8+j][u*16+(l&15)]
__global__ __launch_bounds__(256) void k_prep(
    const float* __restrict__ enc_w, const float* __restrict__ core_w,
    const float* __restrict__ ctx_w, const float* __restrict__ att1_w,
    const float* __restrict__ out_w,
    u16* __restrict__ encT, u16* __restrict__ uvT, u16* __restrict__ ctxT,
    u16* __restrict__ attT, u16* __restrict__ outT)
{
  const int bx = blockIdx.x, tid = threadIdx.x;
  const float* W; u16* D; int NKC, N, local; int uv = 0;
  if (bx < 64)       { W = enc_w;  D = encT; NKC = 16; N = 256; local = bx * 256 + tid; }
  else if (bx < 128) { W = core_w; D = uvT;  NKC = 8;  N = 256; local = (bx-64)*256 + tid; uv = 1; }
  else if (bx < 160) { W = ctx_w;  D = ctxT; NKC = 8;  N = 256; local = (bx-128)*256 + tid; }
  else if (bx < 176) { W = att1_w; D = attT; NKC = 8;  N = 128; local = (bx-160)*256 + tid; }
  else               { W = out_w;  D = outT; NKC = 48; N = 256; local = (bx-176)*256 + tid; }
  const int l  = local & 63;
  const int kc = (local >> 6) % NKC;
  const int u  = (local >> 6) / NKC;
  const int n  = u * 16 + (l & 15);
  const int k0 = kc * 32 + (l >> 4) * 8;
  float f[8];
#pragma unroll
  for (int j = 0; j < 8; ++j) {
    const int k = k0 + j;
    if (uv) f[j] = (n < 256) ? W[(size_t)k * 256 + n] : W[(size_t)(256 + k) * 256 + (n - 256)];
    else    f[j] = W[(size_t)k * N + n];
  }
  uint4 w;
  w.x = pk2(f[0], f[1]); w.y = pk2(f[2], f[3]);
  w.z = pk2(f[4], f[5]); w.w = pk2(f[6], f[7]);
  *(uint4*)&D[(size_t)local * 8] = w;
}

// ============ k_enc: s1 = relu(LN(state @ enc_w + b)) -> s1b (bf16) ============
// tile 64 x 256, row-split (wave wv owns rows wv*16..+15), K=512
__global__ __launch_bounds__(256) void k_enc(
    const float* __restrict__ state, const u16* __restrict__ encT,
    const float* __restrict__ enc_b, const float* __restrict__ enc_g,
    const float* __restrict__ enc_bb, u16* __restrict__ s1b)
{
  __shared__ __align__(16) u16 smA[4 * 64 * 8];    // 4 KB
  __shared__ __align__(16) u16 smB[16 * 64 * 8];   // 16 KB
  const int tid = threadIdx.x, wv = tid >> 6, lane = tid & 63;
  const int cl = lane & 15, quad = lane >> 4;
  const int row0 = blockIdx.x * 64;
  f32x4 acc[16];
#pragma unroll
  for (int u = 0; u < 16; ++u) acc[u] = (f32x4){0.f, 0.f, 0.f, 0.f};

  for (int kc = 0; kc < 16; ++kc) {
    __syncthreads();
    { // A: thread stages unit (t=tid>>6, l=tid&63), fp32 -> bf16
      const int t = tid >> 6, ll = tid & 63;
      const float* src = state + (size_t)(row0 + t * 16 + (ll & 15)) * HH + kc * 32 + (ll >> 4) * 8;
      float4 a = *(const float4*)src, b = *(const float4*)(src + 4);
      uint4 w; w.x = pk2(a.x, a.y); w.y = pk2(a.z, a.w); w.z = pk2(b.x, b.y); w.w = pk2(b.z, b.w);
      *(uint4*)&smA[(size_t)tid * 8] = w;
    }
#pragma unroll
    for (int i = 0; i < 4; ++i) {  // B: wave stages tiles u=wv*4+i
      const int u = wv * 4 + i;
      glds16(encT + ((size_t)(u * 16 + kc) * 64 + lane) * 8, &smB[u * 512]);
    }
    __syncthreads();
    bf16x8 af = frag_ld(&smA[(wv * 64 + lane) * 8]);
#pragma unroll
    for (int u = 0; u < 16; ++u) {
      bf16x8 bf = frag_ld(&smB[(u * 64 + lane) * 8]);
      acc[u] = __builtin_amdgcn_mfma_f32_16x16x32_bf16(af, bf, acc[u], 0, 0, 0);
    }
  }
  float bias[16], gg[16], bb[16];
#pragma unroll
  for (int u = 0; u < 16; ++u) {
    const int col = u * 16 + cl;
    bias[u] = enc_b[col]; gg[u] = enc_g[col]; bb[u] = enc_bb[col];
  }
#pragma unroll
  for (int r4 = 0; r4 < 4; ++r4) {
    float v[16], s = 0.f, sq = 0.f;
#pragma unroll
    for (int u = 0; u < 16; ++u) { v[u] = acc[u][r4] + bias[u]; s += v[u]; sq += v[u] * v[u]; }
    s = red16(s); sq = red16(sq);
    const float mu = s * (1.f / 256.f);
    const float rs = rsqrtf(sq * (1.f / 256.f) - mu * mu + 1e-5f);
    const int row = row0 + wv * 16 + quad * 4 + r4;
#pragma unroll
    for (int u = 0; u < 16; ++u) {
      float o = fmaxf((v[u] - mu) * rs * gg[u] + bb[u], 0.f);
      s1b[(size_t)row * FC + u * 16 + cl] = to_bf16(o);
    }
  }
}

// ============ k_uv: UV = s1 @ [coreW_u | coreW_v] (fp32 out) ============
// tile 64 x 256, col-block by in {0,1}, K=256
__global__ __launch_bounds__(256) void k_uv(
    const u16* __restrict__ s1b, const u16* __restrict__ uvT,
    float* __restrict__ UV)
{
  __shared__ __align__(16) u16 smA[4 * 64 * 8];
  __shared__ __align__(16) u16 smB[16 * 64 * 8];
  const int tid = threadIdx.x, wv = tid >> 6, lane = tid & 63;
  const int cl = lane & 15, quad = lane >> 4;
  const int row0 = blockIdx.x * 64;
  const int cb = blockIdx.y;
  f32x4 acc[16];
#pragma unroll
  for (int u = 0; u < 16; ++u) acc[u] = (f32x4){0.f, 0.f, 0.f, 0.f};

  for (int kc = 0; kc < 8; ++kc) {
    __syncthreads();
    glds16(s1b + (size_t)(row0 + wv * 16 + (lane & 15)) * FC + kc * 32 + (lane >> 4) * 8,
           &smA[wv * 512]);
#pragma unroll
    for (int i = 0; i < 4; ++i) {
      const int u = wv * 4 + i;
      glds16(uvT + ((size_t)((cb * 16 + u) * 8 + kc) * 64 + lane) * 8, &smB[u * 512]);
    }
    __syncthreads();
    bf16x8 af = frag_ld(&smA[(wv * 64 + lane) * 8]);
#pragma unroll
    for (int u = 0; u < 16; ++u) {
      bf16x8 bf = frag_ld(&smB[(u * 64 + lane) * 8]);
      acc[u] = __builtin_amdgcn_mfma_f32_16x16x32_bf16(af, bf, acc[u], 0, 0, 0);
    }
  }
#pragma unroll
  for (int r4 = 0; r4 < 4; ++r4) {
    const int row = row0 + wv * 16 + quad * 4 + r4;
#pragma unroll
    for (int u = 0; u < 16; ++u)
      UV[(size_t)row * 512 + cb * 256 + u * 16 + cl] = acc[u][r4];
  }
}

// ============ k_pair: fused core-build + ctx/att GEMMs + epilogues ============
__global__ __launch_bounds__(256) void k_pair(
    const float* __restrict__ UV, const float* __restrict__ core_b,
    const float* __restrict__ core_g, const float* __restrict__ core_bb,
    const u16* __restrict__ ctxT, const float* __restrict__ ctx_b,
    const float* __restrict__ ctx_g, const float* __restrict__ ctx_bb,
    const u16* __restrict__ attT, const float* __restrict__ att1_b,
    const float* __restrict__ att_g, const float* __restrict__ att_bb,
    const float* __restrict__ att2_w, const float* __restrict__ att2_b,
    u16* __restrict__ effb)
{
  __shared__ __align__(16) u16 smA[2048 * 8];      // 32 KB frag-ordered core; reused as smS
  __shared__ __align__(16) u16 smB[24 * 64 * 8];   // 24 KB B staging
  __shared__ float att_s[64];
  const int g = blockIdx.x;
  const int tid = threadIdx.x, wv = tid >> 6, lane = tid & 63;
  const int cl = lane & 15, quad = lane >> 4;

  // zero A (covers pad rows 56..63)
#pragma unroll
  for (int i = 0; i < 8; ++i)
    *(uint4*)&smA[(size_t)(tid + i * 256) * 8] = (uint4){0u, 0u, 0u, 0u};
  __syncthreads();

  // build core rows p<56 into frag-ordered LDS; lane handles cols l*4..l*4+3
  {
    const int c0 = lane * 4;
    const float4 cb4 = *(const float4*)&core_b[c0];
    const float4 cg4 = *(const float4*)&core_g[c0];
    const float4 cbb4 = *(const float4*)&core_bb[c0];
    for (int p = wv; p < 56; p += 4) {
      const int i = p / 7, t = p - i * 7;
      const int j = t + (t >= i ? 1 : 0);
      const float4 ua = *(const float4*)&UV[(size_t)(g * 8 + i) * 512 + c0];
      const float4 vb = *(const float4*)&UV[(size_t)(g * 8 + j) * 512 + 256 + c0];
      float v[4] = {ua.x + vb.x + cb4.x, ua.y + vb.y + cb4.y,
                    ua.z + vb.z + cb4.z, ua.w + vb.w + cb4.w};
      float s = v[0] + v[1] + v[2] + v[3];
      float sq = v[0]*v[0] + v[1]*v[1] + v[2]*v[2] + v[3]*v[3];
      s = wave_sum64(s); sq = wave_sum64(sq);
      const float mu = s * (1.f / 256.f);
      const float rs = rsqrtf(sq * (1.f / 256.f) - mu * mu + 1e-5f);
      float o0 = fmaxf((v[0] - mu) * rs * cg4.x + cbb4.x, 0.f);
      float o1 = fmaxf((v[1] - mu) * rs * cg4.y + cbb4.y, 0.f);
      float o2 = fmaxf((v[2] - mu) * rs * cg4.z + cbb4.z, 0.f);
      float o3 = fmaxf((v[3] - mu) * rs * cg4.w + cbb4.w, 0.f);
      // frag-order address
      const int idx = (((p >> 4) * 8 + (c0 >> 5)) * 64 + (p & 15) + (((c0 >> 3) & 3) << 4)) * 8 + (c0 & 7);
      uint2 w; w.x = pk2(o0, o1); w.y = pk2(o2, o3);
      *(uint2*)&smA[idx] = w;
    }
  }
  __syncthreads();

  f32x4 accC[16], accT[8];
#pragma unroll
  for (int t = 0; t < 16; ++t) accC[t] = (f32x4){0.f, 0.f, 0.f, 0.f};
#pragma unroll
  for (int t = 0; t < 8; ++t)  accT[t] = (f32x4){0.f, 0.f, 0.f, 0.f};

  for (int kc = 0; kc < 8; ++kc) {
#pragma unroll
    for (int i = 0; i < 6; ++i) {   // wave stages B tiles q=wv*6+i
      const int q = wv * 6 + i;
      if (q < 16) glds16(ctxT + ((size_t)(q * 8 + kc) * 64 + lane) * 8, &smB[q * 512]);
      else        glds16(attT + ((size_t)((q - 16) * 8 + kc) * 64 + lane) * 8, &smB[q * 512]);
    }
    __syncthreads();
    bf16x8 af = frag_ld(&smA[((wv * 8 + kc) * 64 + lane) * 8]);
#pragma unroll
    for (int q = 0; q < 16; ++q) {
      bf16x8 bf = frag_ld(&smB[(q * 64 + lane) * 8]);
      accC[q] = __builtin_amdgcn_mfma_f32_16x16x32_bf16(af, bf, accC[q], 0, 0, 0);
    }
#pragma unroll
    for (int q = 0; q < 8; ++q) {
      bf16x8 bf = frag_ld(&smB[((16 + q) * 64 + lane) * 8]);
      accT[q] = __builtin_amdgcn_mfma_f32_16x16x32_bf16(af, bf, accT[q], 0, 0, 0);
    }
    __syncthreads();
  }

  // ---- att epilogue ----
  const float b2 = att2_b[0];
#pragma unroll
  for (int r4 = 0; r4 < 4; ++r4) {
    float v[8], s = 0.f, sq = 0.f;
#pragma unroll
    for (int t = 0; t < 8; ++t) {
      const int col = t * 16 + cl;
      v[t] = accT[t][r4] + att1_b[col];
      s += v[t]; sq += v[t] * v[t];
    }
    s = red16(s); sq = red16(sq);
    const float mu = s * (1.f / 128.f);
    const float rs = rsqrtf(sq * (1.f / 128.f) - mu * mu + 1e-5f);
    float d = 0.f;
#pragma unroll
    for (int t = 0; t < 8; ++t) {
      const int col = t * 16 + cl;
      float h = tanhf((v[t] - mu) * rs * att_g[col] + att_bb[col]);
      d = fmaf(h, att2_w[col], d);
    }
    d = red16(d);
    if (cl == 0) {
      const int r = wv * 16 + quad * 4 + r4;
      if (r < 56) att_s[r] = 1.f / (1.f + expf(-(d + b2)));
    }
  }
  __syncthreads();

  // ---- ctx epilogue: LN -> relu -> * att -> bf16 into smS (reuse smA) ----
  u16* smS = smA;  // [56][256]
#pragma unroll
  for (int r4 = 0; r4 < 4; ++r4) {
    float v[16], s = 0.f, sq = 0.f;
#pragma unroll
    for (int t = 0; t < 16; ++t) {
      const int col = t * 16 + cl;
      v[t] = accC[t][r4] + ctx_b[col];
      s += v[t]; sq += v[t] * v[t];
    }
    s = red16(s); sq = red16(sq);
    const float mu = s * (1.f / 256.f);
    const float rs = rsqrtf(sq * (1.f / 256.f) - mu * mu + 1e-5f);
    const int r = wv * 16 + quad * 4 + r4;
    if (r < 56) {
      const float ap = att_s[r];
#pragma unroll
      for (int t = 0; t < 16; ++t) {
        const int col = t * 16 + cl;
        float o = fmaxf((v[t] - mu) * rs * ctx_g[col] + ctx_bb[col], 0.f) * ap;
        smS[r * 256 + col] = to_bf16(o);
      }
    }
  }
  __syncthreads();

  // ---- effect[i][c] = sum over 7 partners -> bf16 ----
  const int c = tid;
#pragma unroll
  for (int i = 0; i < 8; ++i) {
    float s = 0.f;
#pragma unroll
    for (int t2 = 0; t2 < 7; ++t2) s += from_bf16(smS[(i * 7 + t2) * 256 + c]);
    effb[(size_t)(g * 8 + i) * FC + c] = to_bf16(s);
  }
}

// ============ k_out: out = [s1|effect|x] @ out_w + out_b (fp32, x2) ============
// tile 64 x 256, K=1536
__global__ __launch_bounds__(256) void k_out(
    const u16* __restrict__ s1b, const u16* __restrict__ effb,
    const float* __restrict__ x, const u16* __restrict__ outT,
    const float* __restrict__ out_b, float* __restrict__ out, int dup)
{
  __shared__ __align__(16) u16 smA[4 * 64 * 8];
  __shared__ __align__(16) u16 smB[16 * 64 * 8];
  const int tid = threadIdx.x, wv = tid >> 6, lane = tid & 63;
  const int cl = lane & 15, quad = lane >> 4;
  const int row0 = blockIdx.x * 64;
  f32x4 acc[16];
#pragma unroll
  for (int u = 0; u < 16; ++u) acc[u] = (f32x4){0.f, 0.f, 0.f, 0.f};

  for (int kc = 0; kc < 48; ++kc) {
    __syncthreads();
    if (kc < 16) {
      const u16* base = (kc < 8) ? s1b : effb;
      const int kof = (kc & 7) * 32;
      glds16(base + (size_t)(row0 + wv * 16 + (lane & 15)) * FC + kof + (lane >> 4) * 8,
             &smA[wv * 512]);
    } else {
      const int t = tid >> 6, ll = tid & 63;
      const float* src = x + (size_t)(row0 + t * 16 + (ll & 15)) * MX + (kc - 16) * 32 + (ll >> 4) * 8;
      float4 a = *(const float4*)src, b = *(const float4*)(src + 4);
      uint4 w; w.x = pk2(a.x, a.y); w.y = pk2(a.z, a.w); w.z = pk2(b.x, b.y); w.w = pk2(b.z, b.w);
      *(uint4*)&smA[(size_t)tid * 8] = w;
    }
#pragma unroll
    for (int i = 0; i < 4; ++i) {
      const int u = wv * 4 + i;
      glds16(outT + ((size_t)(u * 48 + kc) * 64 + lane) * 8, &smB[u * 512]);
    }
    __syncthreads();
    bf16x8 af = frag_ld(&smA[(wv * 64 + lane) * 8]);
#pragma unroll
    for (int u = 0; u < 16; ++u) {
      bf16x8 bf = frag_ld(&smB[(u * 64 + lane) * 8]);
      acc[u] = __builtin_amdgcn_mfma_f32_16x16x32_bf16(af, bf, acc[u], 0, 0, 0);
    }
  }
  float bias[16];
#pragma unroll
  for (int u = 0; u < 16; ++u) bias[u] = out_b[u * 16 + cl];
#pragma unroll
  for (int r4 = 0; r4 < 4; ++r4) {
    const int row = row0 + wv * 16 + quad * 4 + r4;
#pragma unroll
    for (int u = 0; u < 16; ++u) {
      const float o = acc[u][r4] + bias[u];
      out[(size_t)row * FC + u * 16 + cl] = o;
      if (dup) out[(size_t)NROW * FC + (size_t)row * FC + u * 16 + cl] = o;
    }
  }
}

extern "C" void kernel_launch(void* const* d_in, const int* in_sizes, int n_in,
                              void* d_out, int out_size, void* d_ws, size_t ws_size,
                              hipStream_t stream) {
  const float* x      = (const float*)d_in[0];
  const float* state  = (const float*)d_in[1];
  const float* enc_w  = (const float*)d_in[2];
  const float* enc_b  = (const float*)d_in[3];
  const float* enc_g  = (const float*)d_in[4];
  const float* enc_bb = (const float*)d_in[5];
  const float* core_w = (const float*)d_in[6];
  const float* core_b = (const float*)d_in[7];
  const float* core_g = (const float*)d_in[8];
  const float* core_bb= (const float*)d_in[9];
  const float* ctx_w  = (const float*)d_in[10];
  const float* ctx_b  = (const float*)d_in[11];
  const float* ctx_g  = (const float*)d_in[12];
  const float* ctx_bb = (const float*)d_in[13];
  const float* att1_w = (const float*)d_in[14];
  const float* att1_b = (const float*)d_in[15];
  const float* att_g  = (const float*)d_in[16];
  const float* att_bb = (const float*)d_in[17];
  const float* att2_w = (const float*)d_in[18];
  const float* att2_b = (const float*)d_in[19];
  const float* out_w  = (const float*)d_in[20];
  const float* out_b  = (const float*)d_in[21];

  char* ws = (char*)d_ws;
  float* UV  = (float*)ws;                          // 33,554,432 B
  u16* s1b   = (u16*)(ws + 33554432);               //  8,388,608 B
  u16* effb  = (u16*)(ws + 41943040);               //  8,388,608 B
  u16* encT  = (u16*)(ws + 50331648);               //    262,144 B
  u16* uvT   = (u16*)(ws + 50593792);               //    262,144 B
  u16* ctxT  = (u16*)(ws + 50855936);               //    131,072 B
  u16* attT  = (u16*)(ws + 50987008);               //     65,536 B
  u16* outT  = (u16*)(ws + 51052544);               //    786,432 B
  float* out = (float*)d_out;
  const int dup = (out_size >= 2 * NROW * FC) ? 1 : 0;

  k_prep<<<dim3(368), 256, 0, stream>>>(enc_w, core_w, ctx_w, att1_w, out_w,
                                        encT, uvT, ctxT, attT, outT);
  k_enc<<<dim3(NROW / 64), 256, 0, stream>>>(state, encT, enc_b, enc_g, enc_bb, s1b);
  k_uv <<<dim3(NROW / 64, 2), 256, 0, stream>>>(s1b, uvT, UV);
  k_pair<<<dim3(NGRP), 256, 0, stream>>>(UV, core_b, core_g, core_bb,
                                         ctxT, ctx_b, ctx_g, ctx_bb,
                                         attT, att1_b, att_g, att_bb,
                                         att2_w, att2_b, effb);
  k_out<<<dim3(NROW / 64), 256, 0, stream>>>(s1b, effb, x, outT, out_b, out, dup);
}

// Round 4
// 345.139 us; speedup vs baseline: 2.8657x; 1.0479x over previous
//
#include <hip/hip_runtime.h>
#include <stdint.h>

#define FC    256
#define HH    512
#define MX    1024
#define LASTN 128
#define NROW  16384
#define NGRP  2048

typedef unsigned short u16;
typedef __bf16 bf16x8 __attribute__((ext_vector_type(8)));
typedef float  f32x4  __attribute__((ext_vector_type(4)));

__device__ __forceinline__ float red16(float v) {
#pragma unroll
  for (int m = 1; m < 16; m <<= 1) v += __shfl_xor(v, m);
  return v;
}
__device__ __forceinline__ u16 to_bf16(float f) {
  unsigned u = __float_as_uint(f);
  return (u16)((u + 0x8000u) >> 16);
}
__device__ __forceinline__ float from_bf16(u16 s) {
  return __uint_as_float(((unsigned)s) << 16);
}
__device__ __forceinline__ uint32_t pk2(float a, float b) {
  return (uint32_t)to_bf16(a) | ((uint32_t)to_bf16(b) << 16);
}
__device__ __forceinline__ float tanh_fast(float x) {
  float e = __expf(2.f * x);
  return __fdividef(e - 1.f, e + 1.f);
}
__device__ __forceinline__ float sigmoid_fast(float x) {
  return __fdividef(1.f, 1.f + __expf(-x));
}
// async global->LDS, 16B per lane; LDS dest = wave-uniform base + lane*16
__device__ __forceinline__ void glds16(const void* g, void* l) {
  __builtin_amdgcn_global_load_lds(
      (__attribute__((address_space(1))) uint32_t*)g,
      (__attribute__((address_space(3))) uint32_t*)l, 16, 0, 0);
}
__device__ __forceinline__ bf16x8 frag_ld(const u16* p) {
  return __builtin_bit_cast(bf16x8, *(const uint4*)p);
}

// ============ k_prep: weights -> fragment-ordered bf16 global layout ============
// unit id = (u*NKC + kc)*64 + l ; contents j=0..7: W[kc*32+(l>>4)*8+j][u*16+(l&15)]
__global__ __launch_bounds__(256) void k_prep(
    const float* __restrict__ enc_w, const float* __restrict__ core_w,
    const float* __restrict__ ctx_w, const float* __restrict__ att1_w,
    const float* __restrict__ out_w,
    u16* __restrict__ encT, u16* __restrict__ uvT, u16* __restrict__ ctxT,
    u16* __restrict__ attT, u16* __restrict__ outT)
{
  const int bx = blockIdx.x, tid = threadIdx.x;
  const float* W; u16* D; int NKC, N, local; int uv = 0;
  if (bx < 64)       { W = enc_w;  D = encT; NKC = 16; N = 256; local = bx * 256 + tid; }
  else if (bx < 128) { W = core_w; D = uvT;  NKC = 8;  N = 256; local = (bx-64)*256 + tid; uv = 1; }
  else if (bx < 160) { W = ctx_w;  D = ctxT; NKC = 8;  N = 256; local = (bx-128)*256 + tid; }
  else if (bx < 176) { W = att1_w; D = attT; NKC = 8;  N = 128; local = (bx-160)*256 + tid; }
  else               { W = out_w;  D = outT; NKC = 48; N = 256; local = (bx-176)*256 + tid; }
  const int l  = local & 63;
  const int kc = (local >> 6) % NKC;
  const int u  = (local >> 6) / NKC;
  const int n  = u * 16 + (l & 15);
  const int k0 = kc * 32 + (l >> 4) * 8;
  float f[8];
#pragma unroll
  for (int j = 0; j < 8; ++j) {
    const int k = k0 + j;
    if (uv) f[j] = (n < 256) ? W[(size_t)k * 256 + n] : W[(size_t)(256 + k) * 256 + (n - 256)];
    else    f[j] = W[(size_t)k * N + n];
  }
  uint4 w;
  w.x = pk2(f[0], f[1]); w.y = pk2(f[2], f[3]);
  w.z = pk2(f[4], f[5]); w.w = pk2(f[6], f[7]);
  *(uint4*)&D[(size_t)local * 8] = w;
}

// ============ k_enc: s1 = relu(LN(state @ enc_w + b)) -> s1b ============
// tile 32 rows x 256 cols, 512 blocks; wave (rb=wv>>1, cb=wv&1); K=512
__global__ __launch_bounds__(256) void k_enc(
    const float* __restrict__ state, const u16* __restrict__ encT,
    const float* __restrict__ enc_b, const float* __restrict__ enc_g,
    const float* __restrict__ enc_bb, u16* __restrict__ s1b)
{
  __shared__ __align__(16) u16 smA[128 * 8];     // 2 KB
  __shared__ __align__(16) u16 smB[16 * 64 * 8]; // 16 KB
  __shared__ float smP[2][2][16][2];
  const int tid = threadIdx.x, wv = tid >> 6, lane = tid & 63;
  const int cl = lane & 15, quad = lane >> 4;
  const int rb = wv >> 1, cb = wv & 1;
  const int row0 = blockIdx.x * 32;
  f32x4 acc[8];
#pragma unroll
  for (int u = 0; u < 8; ++u) acc[u] = (f32x4){0.f, 0.f, 0.f, 0.f};

  for (int kc = 0; kc < 16; ++kc) {
    __syncthreads();
    if (tid < 128) {   // A stage: unit tid (rowblk=tid>>6, l=tid&63), fp32 -> bf16
      const int rblk = tid >> 6, ll = tid & 63;
      const float* src = state + (size_t)(row0 + rblk * 16 + (ll & 15)) * HH + kc * 32 + (ll >> 4) * 8;
      float4 a = *(const float4*)src, b = *(const float4*)(src + 4);
      uint4 w; w.x = pk2(a.x, a.y); w.y = pk2(a.z, a.w); w.z = pk2(b.x, b.y); w.w = pk2(b.z, b.w);
      *(uint4*)&smA[(size_t)tid * 8] = w;
    }
#pragma unroll
    for (int i = 0; i < 4; ++i) {  // B: wave stages tiles u=wv*4+i
      const int u = wv * 4 + i;
      glds16(encT + ((size_t)(u * 16 + kc) * 64 + lane) * 8, &smB[u * 512]);
    }
    __syncthreads();
    bf16x8 af = frag_ld(&smA[(rb * 64 + lane) * 8]);
#pragma unroll
    for (int u = 0; u < 8; ++u) {
      bf16x8 bf = frag_ld(&smB[((cb * 8 + u) * 64 + lane) * 8]);
      acc[u] = __builtin_amdgcn_mfma_f32_16x16x32_bf16(af, bf, acc[u], 0, 0, 0);
    }
  }
  float bias[8], gg[8], bb[8];
#pragma unroll
  for (int u = 0; u < 8; ++u) {
    const int col = cb * 128 + u * 16 + cl;
    bias[u] = enc_b[col]; gg[u] = enc_g[col]; bb[u] = enc_bb[col];
  }
  float vv[4][8];
#pragma unroll
  for (int r4 = 0; r4 < 4; ++r4) {
    float s = 0.f, sq = 0.f;
#pragma unroll
    for (int u = 0; u < 8; ++u) {
      float v = acc[u][r4] + bias[u];
      vv[r4][u] = v; s += v; sq += v * v;
    }
    s = red16(s); sq = red16(sq);
    if (cl == 0) { smP[cb][rb][quad * 4 + r4][0] = s; smP[cb][rb][quad * 4 + r4][1] = sq; }
  }
  __syncthreads();
#pragma unroll
  for (int r4 = 0; r4 < 4; ++r4) {
    const int rr = quad * 4 + r4;
    const float S  = smP[0][rb][rr][0] + smP[1][rb][rr][0];
    const float SQ = smP[0][rb][rr][1] + smP[1][rb][rr][1];
    const float mu = S * (1.f / 256.f);
    const float rs = rsqrtf(SQ * (1.f / 256.f) - mu * mu + 1e-5f);
    const int row = row0 + rb * 16 + rr;
#pragma unroll
    for (int u = 0; u < 8; ++u) {
      float o = fmaxf((vv[r4][u] - mu) * rs * gg[u] + bb[u], 0.f);
      s1b[(size_t)row * FC + cb * 128 + u * 16 + cl] = to_bf16(o);
    }
  }
}

// ============ k_uv: UV = s1 @ [coreW_u | coreW_v] (fp32 out) ============
// tile 64 x 128; grid (256, 4); K=256
__global__ __launch_bounds__(256) void k_uv(
    const u16* __restrict__ s1b, const u16* __restrict__ uvT,
    float* __restrict__ UV)
{
  __shared__ __align__(16) u16 smA[4 * 64 * 8];   // 4 KB
  __shared__ __align__(16) u16 smB[8 * 64 * 8];   // 8 KB
  const int tid = threadIdx.x, wv = tid >> 6, lane = tid & 63;
  const int cl = lane & 15, quad = lane >> 4;
  const int row0 = blockIdx.x * 64;
  const int nb = blockIdx.y;                      // 0..3 over 512 cols
  f32x4 acc[8];
#pragma unroll
  for (int u = 0; u < 8; ++u) acc[u] = (f32x4){0.f, 0.f, 0.f, 0.f};

  for (int kc = 0; kc < 8; ++kc) {
    __syncthreads();
    glds16(s1b + (size_t)(row0 + wv * 16 + (lane & 15)) * FC + kc * 32 + (lane >> 4) * 8,
           &smA[wv * 512]);
#pragma unroll
    for (int i = 0; i < 2; ++i) {
      const int u = wv * 2 + i;
      glds16(uvT + ((size_t)((nb * 8 + u) * 8 + kc) * 64 + lane) * 8, &smB[u * 512]);
    }
    __syncthreads();
    bf16x8 af = frag_ld(&smA[(wv * 64 + lane) * 8]);
#pragma unroll
    for (int u = 0; u < 8; ++u) {
      bf16x8 bf = frag_ld(&smB[(u * 64 + lane) * 8]);
      acc[u] = __builtin_amdgcn_mfma_f32_16x16x32_bf16(af, bf, acc[u], 0, 0, 0);
    }
  }
#pragma unroll
  for (int r4 = 0; r4 < 4; ++r4) {
    const int row = row0 + wv * 16 + quad * 4 + r4;
#pragma unroll
    for (int u = 0; u < 8; ++u)
      UV[(size_t)row * 512 + nb * 128 + u * 16 + cl] = acc[u][r4];
  }
}

// ============ k_pair: fused core-build + ctx/att GEMMs + epilogues ============
__global__ __launch_bounds__(256, 3) void k_pair(
    const float* __restrict__ UV, const float* __restrict__ core_b,
    const float* __restrict__ core_g, const float* __restrict__ core_bb,
    const u16* __restrict__ ctxT, const float* __restrict__ ctx_b,
    const float* __restrict__ ctx_g, const float* __restrict__ ctx_bb,
    const u16* __restrict__ attT, const float* __restrict__ att1_b,
    const float* __restrict__ att_g, const float* __restrict__ att_bb,
    const float* __restrict__ att2_w, const float* __restrict__ att2_b,
    u16* __restrict__ effb)
{
  __shared__ __align__(16) u16 smA[2048 * 8];    // 32 KB frag-ordered core; reused as smS
  __shared__ __align__(16) u16 smB[16 * 64 * 8]; // 16 KB ctx B staging
  __shared__ float att_s[64];
  const int g = blockIdx.x;
  const int tid = threadIdx.x, wv = tid >> 6, lane = tid & 63;
  const int cl = lane & 15, quad = lane >> 4;

  // zero A (covers pad rows 56..63)
#pragma unroll
  for (int i = 0; i < 8; ++i)
    *(uint4*)&smA[(size_t)(tid + i * 256) * 8] = (uint4){0u, 0u, 0u, 0u};
  __syncthreads();

  // ---- build core: 4 passes, 16 rows/pass (wave: 4 rows, 16 lanes/row) ----
  {
    const int sub = lane >> 4, cl16 = lane & 15;
    const int c0 = cl16 * 16;
    float4 CB[4], CG[4], CBB[4];
#pragma unroll
    for (int q = 0; q < 4; ++q) {
      CB[q]  = *(const float4*)&core_b[c0 + q * 4];
      CG[q]  = *(const float4*)&core_g[c0 + q * 4];
      CBB[q] = *(const float4*)&core_bb[c0 + q * 4];
    }
#pragma unroll
    for (int it = 0; it < 4; ++it) {
      const int p = it * 16 + wv * 4 + sub;
      if (p < 56) {
        const int i = p / 7, t = p - i * 7;
        const int j = t + (t >= i ? 1 : 0);
        const float* uA = UV + (size_t)(g * 8 + i) * 512 + c0;
        const float* vB = UV + (size_t)(g * 8 + j) * 512 + 256 + c0;
        float v[16];
        float s = 0.f, sq = 0.f;
#pragma unroll
        for (int q = 0; q < 4; ++q) {
          float4 ua = *(const float4*)(uA + q * 4);
          float4 vb = *(const float4*)(vB + q * 4);
          float x0 = ua.x + vb.x + CB[q].x, x1 = ua.y + vb.y + CB[q].y;
          float x2 = ua.z + vb.z + CB[q].z, x3 = ua.w + vb.w + CB[q].w;
          v[q*4+0] = x0; v[q*4+1] = x1; v[q*4+2] = x2; v[q*4+3] = x3;
          s += x0 + x1 + x2 + x3;
          sq += x0*x0 + x1*x1 + x2*x2 + x3*x3;
        }
        s = red16(s); sq = red16(sq);
        const float mu = s * (1.f / 256.f);
        const float rs = rsqrtf(sq * (1.f / 256.f) - mu * mu + 1e-5f);
        float o[16];
#pragma unroll
        for (int q = 0; q < 4; ++q) {
          o[q*4+0] = fmaxf((v[q*4+0] - mu) * rs * CG[q].x + CBB[q].x, 0.f);
          o[q*4+1] = fmaxf((v[q*4+1] - mu) * rs * CG[q].y + CBB[q].y, 0.f);
          o[q*4+2] = fmaxf((v[q*4+2] - mu) * rs * CG[q].z + CBB[q].z, 0.f);
          o[q*4+3] = fmaxf((v[q*4+3] - mu) * rs * CG[q].w + CBB[q].w, 0.f);
        }
        // frag-order write: rowblk=p>>4, kblk=cl16>>1, twid=(cl16&1)*2 (+1 for 2nd half)
        const int base = ((p >> 4) * 8 + (cl16 >> 1)) * 64;
        const int lane1 = (p & 15) + 16 * ((cl16 & 1) * 2);
        uint4 w1, w2;
        w1.x = pk2(o[0], o[1]);  w1.y = pk2(o[2], o[3]);
        w1.z = pk2(o[4], o[5]);  w1.w = pk2(o[6], o[7]);
        w2.x = pk2(o[8], o[9]);  w2.y = pk2(o[10], o[11]);
        w2.z = pk2(o[12], o[13]); w2.w = pk2(o[14], o[15]);
        *(uint4*)&smA[(size_t)(base + lane1) * 8] = w1;
        *(uint4*)&smA[(size_t)(base + lane1 + 16) * 8] = w2;
      }
    }
  }
  __syncthreads();

  f32x4 accC[16], accT[8];
#pragma unroll
  for (int t = 0; t < 16; ++t) accC[t] = (f32x4){0.f, 0.f, 0.f, 0.f};
#pragma unroll
  for (int t = 0; t < 8; ++t)  accT[t] = (f32x4){0.f, 0.f, 0.f, 0.f};

  for (int kc = 0; kc < 8; ++kc) {
    if (kc) __syncthreads();   // smB free (prev reads done)
#pragma unroll
    for (int i = 0; i < 4; ++i) {   // ctx B tiles via LDS
      const int q = wv * 4 + i;
      glds16(ctxT + ((size_t)(q * 8 + kc) * 64 + lane) * 8, &smB[q * 512]);
    }
    uint4 attf[8];
#pragma unroll
    for (int q = 0; q < 8; ++q)     // att B frags direct to registers (L2-hot)
      attf[q] = *(const uint4*)(attT + ((size_t)(q * 8 + kc) * 64 + lane) * 8);
    __syncthreads();                // smB ready
    bf16x8 af = frag_ld(&smA[((wv * 8 + kc) * 64 + lane) * 8]);
#pragma unroll
    for (int q = 0; q < 16; ++q) {
      bf16x8 bf = frag_ld(&smB[(q * 64 + lane) * 8]);
      accC[q] = __builtin_amdgcn_mfma_f32_16x16x32_bf16(af, bf, accC[q], 0, 0, 0);
    }
#pragma unroll
    for (int q = 0; q < 8; ++q) {
      bf16x8 bf = __builtin_bit_cast(bf16x8, attf[q]);
      accT[q] = __builtin_amdgcn_mfma_f32_16x16x32_bf16(af, bf, accT[q], 0, 0, 0);
    }
  }

  // ---- att epilogue ----
  {
    float ab[8], ag[8], abb[8], aw[8];
#pragma unroll
    for (int t = 0; t < 8; ++t) {
      const int col = t * 16 + cl;
      ab[t] = att1_b[col]; ag[t] = att_g[col]; abb[t] = att_bb[col]; aw[t] = att2_w[col];
    }
    const float b2 = att2_b[0];
#pragma unroll
    for (int r4 = 0; r4 < 4; ++r4) {
      float v[8], s = 0.f, sq = 0.f;
#pragma unroll
      for (int t = 0; t < 8; ++t) {
        v[t] = accT[t][r4] + ab[t];
        s += v[t]; sq += v[t] * v[t];
      }
      s = red16(s); sq = red16(sq);
      const float mu = s * (1.f / 128.f);
      const float rs = rsqrtf(sq * (1.f / 128.f) - mu * mu + 1e-5f);
      float d = 0.f;
#pragma unroll
      for (int t = 0; t < 8; ++t) {
        float h = tanh_fast((v[t] - mu) * rs * ag[t] + abb[t]);
        d = fmaf(h, aw[t], d);
      }
      d = red16(d);
      if (cl == 0) {
        const int r = wv * 16 + quad * 4 + r4;
        if (r < 56) att_s[r] = sigmoid_fast(d + b2);
      }
    }
  }
  __syncthreads();   // all smA GEMM reads done + att_s visible

  // ---- ctx epilogue: LN -> relu -> * att -> bf16 into smS (stride 264) ----
  u16* smS = smA;
  {
    float cb[16], cg[16], cbb[16];
#pragma unroll
    for (int t = 0; t < 16; ++t) {
      const int col = t * 16 + cl;
      cb[t] = ctx_b[col]; cg[t] = ctx_g[col]; cbb[t] = ctx_bb[col];
    }
#pragma unroll
    for (int r4 = 0; r4 < 4; ++r4) {
      float v[16], s = 0.f, sq = 0.f;
#pragma unroll
      for (int t = 0; t < 16; ++t) {
        v[t] = accC[t][r4] + cb[t];
        s += v[t]; sq += v[t] * v[t];
      }
      s = red16(s); sq = red16(sq);
      const float mu = s * (1.f / 256.f);
      const float rs = rsqrtf(sq * (1.f / 256.f) - mu * mu + 1e-5f);
      const int r = wv * 16 + quad * 4 + r4;
      if (r < 56) {
        const float ap = att_s[r];
#pragma unroll
        for (int t = 0; t < 16; ++t) {
          const int col = t * 16 + cl;
          float o = fmaxf((v[t] - mu) * rs * cg[t] + cbb[t], 0.f) * ap;
          smS[r * 264 + col] = to_bf16(o);
        }
      }
    }
  }
  __syncthreads();

  // ---- effect[i][c] = sum over 7 partners -> bf16 ----
  const int c = tid;
#pragma unroll
  for (int i = 0; i < 8; ++i) {
    float s = 0.f;
#pragma unroll
    for (int t2 = 0; t2 < 7; ++t2) s += from_bf16(smS[(i * 7 + t2) * 264 + c]);
    effb[(size_t)(g * 8 + i) * FC + c] = to_bf16(s);
  }
}

// ============ k_out: out = [s1|effect|x] @ out_w + out_b (fp32, x2) ============
// tile 64 x 128; grid (256, 2); K=1536
__global__ __launch_bounds__(256) void k_out(
    const u16* __restrict__ s1b, const u16* __restrict__ effb,
    const float* __restrict__ x, const u16* __restrict__ outT,
    const float* __restrict__ out_b, float* __restrict__ out, int dup)
{
  __shared__ __align__(16) u16 smA[4 * 64 * 8];   // 4 KB
  __shared__ __align__(16) u16 smB[8 * 64 * 8];   // 8 KB
  const int tid = threadIdx.x, wv = tid >> 6, lane = tid & 63;
  const int cl = lane & 15, quad = lane >> 4;
  const int row0 = blockIdx.x * 64;
  const int nb = blockIdx.y;
  f32x4 acc[8];
#pragma unroll
  for (int u = 0; u < 8; ++u) acc[u] = (f32x4){0.f, 0.f, 0.f, 0.f};

  for (int kc = 0; kc < 48; ++kc) {
    __syncthreads();
    if (kc < 16) {
      const u16* base = (kc < 8) ? s1b : effb;
      const int kof = (kc & 7) * 32;
      glds16(base + (size_t)(row0 + wv * 16 + (lane & 15)) * FC + kof + (lane >> 4) * 8,
             &smA[wv * 512]);
    } else {
      const int t = tid >> 6, ll = tid & 63;
      const float* src = x + (size_t)(row0 + t * 16 + (ll & 15)) * MX + (kc - 16) * 32 + (ll >> 4) * 8;
      float4 a = *(const float4*)src, b = *(const float4*)(src + 4);
      uint4 w; w.x = pk2(a.x, a.y); w.y = pk2(a.z, a.w); w.z = pk2(b.x, b.y); w.w = pk2(b.z, b.w);
      *(uint4*)&smA[(size_t)tid * 8] = w;
    }
#pragma unroll
    for (int i = 0; i < 2; ++i) {
      const int u = wv * 2 + i;
      glds16(outT + ((size_t)((nb * 8 + u) * 48 + kc) * 64 + lane) * 8, &smB[u * 512]);
    }
    __syncthreads();
    bf16x8 af = frag_ld(&smA[(wv * 64 + lane) * 8]);
#pragma unroll
    for (int u = 0; u < 8; ++u) {
      bf16x8 bf = frag_ld(&smB[(u * 64 + lane) * 8]);
      acc[u] = __builtin_amdgcn_mfma_f32_16x16x32_bf16(af, bf, acc[u], 0, 0, 0);
    }
  }
  float bias[8];
#pragma unroll
  for (int u = 0; u < 8; ++u) bias[u] = out_b[nb * 128 + u * 16 + cl];
#pragma unroll
  for (int r4 = 0; r4 < 4; ++r4) {
    const int row = row0 + wv * 16 + quad * 4 + r4;
#pragma unroll
    for (int u = 0; u < 8; ++u) {
      const float o = acc[u][r4] + bias[u];
      const size_t off = (size_t)row * FC + nb * 128 + u * 16 + cl;
      out[off] = o;
      if (dup) out[(size_t)NROW * FC + off] = o;
    }
  }
}

extern "C" void kernel_launch(void* const* d_in, const int* in_sizes, int n_in,
                              void* d_out, int out_size, void* d_ws, size_t ws_size,
                              hipStream_t stream) {
  const float* x      = (const float*)d_in[0];
  const float* state  = (const float*)d_in[1];
  const float* enc_w  = (const float*)d_in[2];
  const float* enc_b  = (const float*)d_in[3];
  const float* enc_g  = (const float*)d_in[4];
  const float* enc_bb = (const float*)d_in[5];
  const float* core_w = (const float*)d_in[6];
  const float* core_b = (const float*)d_in[7];
  const float* core_g = (const float*)d_in[8];
  const float* core_bb= (const float*)d_in[9];
  const float* ctx_w  = (const float*)d_in[10];
  const float* ctx_b  = (const float*)d_in[11];
  const float* ctx_g  = (const float*)d_in[12];
  const float* ctx_bb = (const float*)d_in[13];
  const float* att1_w = (const float*)d_in[14];
  const float* att1_b = (const float*)d_in[15];
  const float* att_g  = (const float*)d_in[16];
  const float* att_bb = (const float*)d_in[17];
  const float* att2_w = (const float*)d_in[18];
  const float* att2_b = (const float*)d_in[19];
  const float* out_w  = (const float*)d_in[20];
  const float* out_b  = (const float*)d_in[21];

  char* ws = (char*)d_ws;
  float* UV  = (float*)ws;                          // 33,554,432 B
  u16* s1b   = (u16*)(ws + 33554432);               //  8,388,608 B
  u16* effb  = (u16*)(ws + 41943040);               //  8,388,608 B
  u16* encT  = (u16*)(ws + 50331648);               //    262,144 B
  u16* uvT   = (u16*)(ws + 50593792);               //    262,144 B
  u16* ctxT  = (u16*)(ws + 50855936);               //    131,072 B
  u16* attT  = (u16*)(ws + 50987008);               //     65,536 B
  u16* outT  = (u16*)(ws + 51052544);               //    786,432 B
  float* out = (float*)d_out;
  const int dup = (out_size >= 2 * NROW * FC) ? 1 : 0;

  k_prep<<<dim3(368), 256, 0, stream>>>(enc_w, core_w, ctx_w, att1_w, out_w,
                                        encT, uvT, ctxT, attT, outT);
  k_enc<<<dim3(NROW / 32), 256, 0, stream>>>(state, encT, enc_b, enc_g, enc_bb, s1b);
  k_uv <<<dim3(NROW / 64, 4), 256, 0, stream>>>(s1b, uvT, UV);
  k_pair<<<dim3(NGRP), 256, 0, stream>>>(UV, core_b, core_g, core_bb,
                                         ctxT, ctx_b, ctx_g, ctx_bb,
                                         attT, att1_b, att_g, att_bb,
                                         att2_w, att2_b, effb);
  k_out<<<dim3(NROW / 64, 2), 256, 0, stream>>>(s1b, effb, x, outT, out_b, out, dup);
}

// Round 5
// 303.641 us; speedup vs baseline: 3.2574x; 1.1367x over previous
//
#include <hip/hip_runtime.h>
#include <stdint.h>

#define FC    256
#define HH    512
#define MX    1024
#define LASTN 128
#define NROW  16384
#define NGRP  2048

typedef unsigned short u16;
typedef __bf16 bf16x8 __attribute__((ext_vector_type(8)));
typedef float  f32x4  __attribute__((ext_vector_type(4)));

__device__ __forceinline__ float red16(float v) {
#pragma unroll
  for (int m = 1; m < 16; m <<= 1) v += __shfl_xor(v, m);
  return v;
}
__device__ __forceinline__ u16 to_bf16(float f) {
  unsigned u = __float_as_uint(f);
  return (u16)((u + 0x8000u) >> 16);
}
__device__ __forceinline__ float from_bf16(u16 s) {
  return __uint_as_float(((unsigned)s) << 16);
}
__device__ __forceinline__ uint32_t pk2(float a, float b) {
  return (uint32_t)to_bf16(a) | ((uint32_t)to_bf16(b) << 16);
}
__device__ __forceinline__ float tanh_fast(float x) {
  float e = __expf(2.f * x);
  return __fdividef(e - 1.f, e + 1.f);
}
__device__ __forceinline__ float sigmoid_fast(float x) {
  return __fdividef(1.f, 1.f + __expf(-x));
}
// async global->LDS, 16B per lane; LDS dest = wave-uniform base + lane*16
__device__ __forceinline__ void glds16(const void* g, void* l) {
  __builtin_amdgcn_global_load_lds(
      (__attribute__((address_space(1))) uint32_t*)g,
      (__attribute__((address_space(3))) uint32_t*)l, 16, 0, 0);
}
__device__ __forceinline__ bf16x8 frag_ld(const u16* p) {
  return __builtin_bit_cast(bf16x8, *(const uint4*)p);
}

// ============ k_prep: weights -> fragment-ordered bf16 global layout ============
// unit id = (u*NKC + kc)*64 + l ; contents j=0..7: W[kc*32+(l>>4)*8+j][u*16+(l&15)]
__global__ __launch_bounds__(256) void k_prep(
    const float* __restrict__ enc_w, const float* __restrict__ core_w,
    const float* __restrict__ ctx_w, const float* __restrict__ att1_w,
    const float* __restrict__ out_w,
    u16* __restrict__ encT, u16* __restrict__ uvT, u16* __restrict__ ctxT,
    u16* __restrict__ attT, u16* __restrict__ outT)
{
  const int bx = blockIdx.x, tid = threadIdx.x;
  const float* W; u16* D; int NKC, N, local; int uv = 0;
  if (bx < 64)       { W = enc_w;  D = encT; NKC = 16; N = 256; local = bx * 256 + tid; }
  else if (bx < 128) { W = core_w; D = uvT;  NKC = 8;  N = 256; local = (bx-64)*256 + tid; uv = 1; }
  else if (bx < 160) { W = ctx_w;  D = ctxT; NKC = 8;  N = 256; local = (bx-128)*256 + tid; }
  else if (bx < 176) { W = att1_w; D = attT; NKC = 8;  N = 128; local = (bx-160)*256 + tid; }
  else               { W = out_w;  D = outT; NKC = 48; N = 256; local = (bx-176)*256 + tid; }
  const int l  = local & 63;
  const int kc = (local >> 6) % NKC;
  const int u  = (local >> 6) / NKC;
  const int n  = u * 16 + (l & 15);
  const int k0 = kc * 32 + (l >> 4) * 8;
  float f[8];
#pragma unroll
  for (int j = 0; j < 8; ++j) {
    const int k = k0 + j;
    if (uv) f[j] = (n < 256) ? W[(size_t)k * 256 + n] : W[(size_t)(256 + k) * 256 + (n - 256)];
    else    f[j] = W[(size_t)k * N + n];
  }
  uint4 w;
  w.x = pk2(f[0], f[1]); w.y = pk2(f[2], f[3]);
  w.z = pk2(f[4], f[5]); w.w = pk2(f[6], f[7]);
  *(uint4*)&D[(size_t)local * 8] = w;
}

// ============ k_enc: s1 = relu(LN(state @ enc_w + b)) -> s1b ============
// tile 32 rows x 256 cols, 512 blocks; wave (rb=wv>>1, cb=wv&1); K=512 in pairs
__global__ __launch_bounds__(256) void k_enc(
    const float* __restrict__ state, const u16* __restrict__ encT,
    const float* __restrict__ enc_b, const float* __restrict__ enc_g,
    const float* __restrict__ enc_bb, u16* __restrict__ s1b)
{
  __shared__ __align__(16) u16 smA[2][128 * 8];     // 2 x 2 KB
  __shared__ __align__(16) u16 smB[2][16 * 64 * 8]; // 2 x 16 KB
  __shared__ float smP[2][2][16][2];
  const int tid = threadIdx.x, wv = tid >> 6, lane = tid & 63;
  const int cl = lane & 15, quad = lane >> 4;
  const int rb = wv >> 1, cb = wv & 1;
  const int row0 = blockIdx.x * 32;
  f32x4 acc[8];
#pragma unroll
  for (int u = 0; u < 8; ++u) acc[u] = (f32x4){0.f, 0.f, 0.f, 0.f};

  for (int kk = 0; kk < 8; ++kk) {
    __syncthreads();
    { // A: each thread stages unit (p=tid>>7, lu=tid&127), fp32 -> bf16
      const int p = tid >> 7, lu = tid & 127;
      const int kc = kk * 2 + p;
      const int rblk = lu >> 6, ll = lu & 63;
      const float* src = state + (size_t)(row0 + rblk * 16 + (ll & 15)) * HH + kc * 32 + (ll >> 4) * 8;
      float4 a = *(const float4*)src, b = *(const float4*)(src + 4);
      uint4 w; w.x = pk2(a.x, a.y); w.y = pk2(a.z, a.w); w.z = pk2(b.x, b.y); w.w = pk2(b.z, b.w);
      *(uint4*)&smA[p][(size_t)lu * 8] = w;
    }
#pragma unroll
    for (int p = 0; p < 2; ++p)
#pragma unroll
      for (int i = 0; i < 4; ++i) {
        const int u = wv * 4 + i;
        glds16(encT + ((size_t)(u * 16 + kk * 2 + p) * 64 + lane) * 8, &smB[p][u * 512]);
      }
    __syncthreads();
#pragma unroll
    for (int p = 0; p < 2; ++p) {
      bf16x8 af = frag_ld(&smA[p][(rb * 64 + lane) * 8]);
#pragma unroll
      for (int u = 0; u < 8; ++u) {
        bf16x8 bf = frag_ld(&smB[p][((cb * 8 + u) * 64 + lane) * 8]);
        acc[u] = __builtin_amdgcn_mfma_f32_16x16x32_bf16(af, bf, acc[u], 0, 0, 0);
      }
    }
  }
  float bias[8], gg[8], bb[8];
#pragma unroll
  for (int u = 0; u < 8; ++u) {
    const int col = cb * 128 + u * 16 + cl;
    bias[u] = enc_b[col]; gg[u] = enc_g[col]; bb[u] = enc_bb[col];
  }
  float vv[4][8];
#pragma unroll
  for (int r4 = 0; r4 < 4; ++r4) {
    float s = 0.f, sq = 0.f;
#pragma unroll
    for (int u = 0; u < 8; ++u) {
      float v = acc[u][r4] + bias[u];
      vv[r4][u] = v; s += v; sq += v * v;
    }
    s = red16(s); sq = red16(sq);
    if (cl == 0) { smP[cb][rb][quad * 4 + r4][0] = s; smP[cb][rb][quad * 4 + r4][1] = sq; }
  }
  __syncthreads();
#pragma unroll
  for (int r4 = 0; r4 < 4; ++r4) {
    const int rr = quad * 4 + r4;
    const float S  = smP[0][rb][rr][0] + smP[1][rb][rr][0];
    const float SQ = smP[0][rb][rr][1] + smP[1][rb][rr][1];
    const float mu = S * (1.f / 256.f);
    const float rs = rsqrtf(SQ * (1.f / 256.f) - mu * mu + 1e-5f);
    const int row = row0 + rb * 16 + rr;
#pragma unroll
    for (int u = 0; u < 8; ++u) {
      float o = fmaxf((vv[r4][u] - mu) * rs * gg[u] + bb[u], 0.f);
      s1b[(size_t)row * FC + cb * 128 + u * 16 + cl] = to_bf16(o);
    }
  }
}

// ============ k_uv: UV = s1 @ [coreW_u | coreW_v] (fp32 out) ============
// tile 64 x 128; grid (256, 4); K=256 in pairs
__global__ __launch_bounds__(256) void k_uv(
    const u16* __restrict__ s1b, const u16* __restrict__ uvT,
    float* __restrict__ UV)
{
  __shared__ __align__(16) u16 smA[2][4 * 64 * 8];   // 2 x 4 KB
  __shared__ __align__(16) u16 smB[2][8 * 64 * 8];   // 2 x 8 KB
  const int tid = threadIdx.x, wv = tid >> 6, lane = tid & 63;
  const int cl = lane & 15, quad = lane >> 4;
  const int row0 = blockIdx.x * 64;
  const int nb = blockIdx.y;                         // 0..3 over 512 cols
  f32x4 acc[8];
#pragma unroll
  for (int u = 0; u < 8; ++u) acc[u] = (f32x4){0.f, 0.f, 0.f, 0.f};

  for (int kk = 0; kk < 4; ++kk) {
    __syncthreads();
#pragma unroll
    for (int p = 0; p < 2; ++p) {
      const int kc = kk * 2 + p;
      glds16(s1b + (size_t)(row0 + wv * 16 + (lane & 15)) * FC + kc * 32 + (lane >> 4) * 8,
             &smA[p][wv * 512]);
#pragma unroll
      for (int i = 0; i < 2; ++i) {
        const int u = wv * 2 + i;
        glds16(uvT + ((size_t)((nb * 8 + u) * 8 + kc) * 64 + lane) * 8, &smB[p][u * 512]);
      }
    }
    __syncthreads();
#pragma unroll
    for (int p = 0; p < 2; ++p) {
      bf16x8 af = frag_ld(&smA[p][(wv * 64 + lane) * 8]);
#pragma unroll
      for (int u = 0; u < 8; ++u) {
        bf16x8 bf = frag_ld(&smB[p][(u * 64 + lane) * 8]);
        acc[u] = __builtin_amdgcn_mfma_f32_16x16x32_bf16(af, bf, acc[u], 0, 0, 0);
      }
    }
  }
#pragma unroll
  for (int r4 = 0; r4 < 4; ++r4) {
    const int row = row0 + wv * 16 + quad * 4 + r4;
#pragma unroll
    for (int u = 0; u < 8; ++u)
      UV[(size_t)row * 512 + nb * 128 + u * 16 + cl] = acc[u][r4];
  }
}

// ============ k_pair: fused core-build + ctx/att GEMMs + epilogues ============
__global__ __launch_bounds__(256, 2) void k_pair(
    const float* __restrict__ UV, const float* __restrict__ core_b,
    const float* __restrict__ core_g, const float* __restrict__ core_bb,
    const u16* __restrict__ ctxT, const float* __restrict__ ctx_b,
    const float* __restrict__ ctx_g, const float* __restrict__ ctx_bb,
    const u16* __restrict__ attT, const float* __restrict__ att1_b,
    const float* __restrict__ att_g, const float* __restrict__ att_bb,
    const float* __restrict__ att2_w, const float* __restrict__ att2_b,
    u16* __restrict__ effb)
{
  __shared__ __align__(16) u16 smA[2048 * 8];     // 32 KB frag-ordered core; reused as smS
  __shared__ __align__(16) u16 smB[16 * 64 * 8];  // 16 KB ctx B staging
  __shared__ __align__(16) float smUV[16 * 256];  // 16 KB: rows 0..7 = U, 8..15 = V
  __shared__ float att_s[64];
  const int g = blockIdx.x;
  const int tid = threadIdx.x, wv = tid >> 6, lane = tid & 63;
  const int cl = lane & 15, quad = lane >> 4;

  // prefetch this group's 16 UV rows into LDS (async, overlapped with smA zeroing)
#pragma unroll
  for (int i = 0; i < 4; ++i) {
    const int r = wv * 4 + i;                 // 0..15
    const int row = g * 8 + (r & 7);
    const int half = r >> 3;
    glds16(UV + (size_t)row * 512 + half * 256 + lane * 4, &smUV[r * 256]);
  }
  // zero A (covers pad rows 56..63)
#pragma unroll
  for (int i = 0; i < 8; ++i)
    *(uint4*)&smA[(size_t)(tid + i * 256) * 8] = (uint4){0u, 0u, 0u, 0u};
  __syncthreads();   // drains glds too

  // ---- build core from LDS: 4 passes, 16 rows/pass (wave: 4 rows x 16 lanes) ----
  {
    const int sub = lane >> 4, cl16 = lane & 15;
    const int c0 = cl16 * 16;
    float4 CB[4], CG[4], CBB[4];
#pragma unroll
    for (int q = 0; q < 4; ++q) {
      CB[q]  = *(const float4*)&core_b[c0 + q * 4];
      CG[q]  = *(const float4*)&core_g[c0 + q * 4];
      CBB[q] = *(const float4*)&core_bb[c0 + q * 4];
    }
#pragma unroll
    for (int it = 0; it < 4; ++it) {
      const int p = it * 16 + wv * 4 + sub;
      if (p < 56) {
        const int i = p / 7, t = p - i * 7;
        const int j = t + (t >= i ? 1 : 0);
        const float* uA = &smUV[i * 256 + c0];
        const float* vB = &smUV[(8 + j) * 256 + c0];
        float v[16];
        float s = 0.f, sq = 0.f;
#pragma unroll
        for (int q = 0; q < 4; ++q) {
          float4 ua = *(const float4*)(uA + q * 4);
          float4 vb = *(const float4*)(vB + q * 4);
          float x0 = ua.x + vb.x + CB[q].x, x1 = ua.y + vb.y + CB[q].y;
          float x2 = ua.z + vb.z + CB[q].z, x3 = ua.w + vb.w + CB[q].w;
          v[q*4+0] = x0; v[q*4+1] = x1; v[q*4+2] = x2; v[q*4+3] = x3;
          s += x0 + x1 + x2 + x3;
          sq += x0*x0 + x1*x1 + x2*x2 + x3*x3;
        }
        s = red16(s); sq = red16(sq);
        const float mu = s * (1.f / 256.f);
        const float rs = rsqrtf(sq * (1.f / 256.f) - mu * mu + 1e-5f);
        float o[16];
#pragma unroll
        for (int q = 0; q < 4; ++q) {
          o[q*4+0] = fmaxf((v[q*4+0] - mu) * rs * CG[q].x + CBB[q].x, 0.f);
          o[q*4+1] = fmaxf((v[q*4+1] - mu) * rs * CG[q].y + CBB[q].y, 0.f);
          o[q*4+2] = fmaxf((v[q*4+2] - mu) * rs * CG[q].z + CBB[q].z, 0.f);
          o[q*4+3] = fmaxf((v[q*4+3] - mu) * rs * CG[q].w + CBB[q].w, 0.f);
        }
        const int base = ((p >> 4) * 8 + (cl16 >> 1)) * 64;
        const int lane1 = (p & 15) + 16 * ((cl16 & 1) * 2);
        uint4 w1, w2;
        w1.x = pk2(o[0], o[1]);  w1.y = pk2(o[2], o[3]);
        w1.z = pk2(o[4], o[5]);  w1.w = pk2(o[6], o[7]);
        w2.x = pk2(o[8], o[9]);  w2.y = pk2(o[10], o[11]);
        w2.z = pk2(o[12], o[13]); w2.w = pk2(o[14], o[15]);
        *(uint4*)&smA[(size_t)(base + lane1) * 8] = w1;
        *(uint4*)&smA[(size_t)(base + lane1 + 16) * 8] = w2;
      }
    }
  }
  __syncthreads();

  f32x4 accC[16], accT[8];
#pragma unroll
  for (int t = 0; t < 16; ++t) accC[t] = (f32x4){0.f, 0.f, 0.f, 0.f};
#pragma unroll
  for (int t = 0; t < 8; ++t)  accT[t] = (f32x4){0.f, 0.f, 0.f, 0.f};

  for (int kc = 0; kc < 8; ++kc) {
    if (kc) __syncthreads();   // smB free (prev reads done)
#pragma unroll
    for (int i = 0; i < 4; ++i) {   // ctx B tiles via LDS
      const int q = wv * 4 + i;
      glds16(ctxT + ((size_t)(q * 8 + kc) * 64 + lane) * 8, &smB[q * 512]);
    }
    uint4 attf[8];
#pragma unroll
    for (int q = 0; q < 8; ++q)     // att B frags direct to registers (L2-hot)
      attf[q] = *(const uint4*)(attT + ((size_t)(q * 8 + kc) * 64 + lane) * 8);
    __syncthreads();                // smB ready
    bf16x8 af = frag_ld(&smA[((wv * 8 + kc) * 64 + lane) * 8]);
#pragma unroll
    for (int q = 0; q < 16; ++q) {
      bf16x8 bf = frag_ld(&smB[(q * 64 + lane) * 8]);
      accC[q] = __builtin_amdgcn_mfma_f32_16x16x32_bf16(af, bf, accC[q], 0, 0, 0);
    }
#pragma unroll
    for (int q = 0; q < 8; ++q) {
      bf16x8 bf = __builtin_bit_cast(bf16x8, attf[q]);
      accT[q] = __builtin_amdgcn_mfma_f32_16x16x32_bf16(af, bf, accT[q], 0, 0, 0);
    }
  }

  // ---- att epilogue ----
  {
    float ab[8], ag[8], abb[8], aw[8];
#pragma unroll
    for (int t = 0; t < 8; ++t) {
      const int col = t * 16 + cl;
      ab[t] = att1_b[col]; ag[t] = att_g[col]; abb[t] = att_bb[col]; aw[t] = att2_w[col];
    }
    const float b2 = att2_b[0];
#pragma unroll
    for (int r4 = 0; r4 < 4; ++r4) {
      float v[8], s = 0.f, sq = 0.f;
#pragma unroll
      for (int t = 0; t < 8; ++t) {
        v[t] = accT[t][r4] + ab[t];
        s += v[t]; sq += v[t] * v[t];
      }
      s = red16(s); sq = red16(sq);
      const float mu = s * (1.f / 128.f);
      const float rs = rsqrtf(sq * (1.f / 128.f) - mu * mu + 1e-5f);
      float d = 0.f;
#pragma unroll
      for (int t = 0; t < 8; ++t) {
        float h = tanh_fast((v[t] - mu) * rs * ag[t] + abb[t]);
        d = fmaf(h, aw[t], d);
      }
      d = red16(d);
      if (cl == 0) {
        const int r = wv * 16 + quad * 4 + r4;
        if (r < 56) att_s[r] = sigmoid_fast(d + b2);
      }
    }
  }
  __syncthreads();   // all smA GEMM reads done + att_s visible

  // ---- ctx epilogue: LN -> relu -> * att -> bf16 into smS (stride 264) ----
  u16* smS = smA;
  {
    float cb[16], cg[16], cbb[16];
#pragma unroll
    for (int t = 0; t < 16; ++t) {
      const int col = t * 16 + cl;
      cb[t] = ctx_b[col]; cg[t] = ctx_g[col]; cbb[t] = ctx_bb[col];
    }
#pragma unroll
    for (int r4 = 0; r4 < 4; ++r4) {
      float v[16], s = 0.f, sq = 0.f;
#pragma unroll
      for (int t = 0; t < 16; ++t) {
        v[t] = accC[t][r4] + cb[t];
        s += v[t]; sq += v[t] * v[t];
      }
      s = red16(s); sq = red16(sq);
      const float mu = s * (1.f / 256.f);
      const float rs = rsqrtf(sq * (1.f / 256.f) - mu * mu + 1e-5f);
      const int r = wv * 16 + quad * 4 + r4;
      if (r < 56) {
        const float ap = att_s[r];
#pragma unroll
        for (int t = 0; t < 16; ++t) {
          const int col = t * 16 + cl;
          float o = fmaxf((v[t] - mu) * rs * cg[t] + cbb[t], 0.f) * ap;
          smS[r * 264 + col] = to_bf16(o);
        }
      }
    }
  }
  __syncthreads();

  // ---- effect[i][c] = sum over 7 partners -> bf16 ----
  const int c = tid;
#pragma unroll
  for (int i = 0; i < 8; ++i) {
    float s = 0.f;
#pragma unroll
    for (int t2 = 0; t2 < 7; ++t2) s += from_bf16(smS[(i * 7 + t2) * 264 + c]);
    effb[(size_t)(g * 8 + i) * FC + c] = to_bf16(s);
  }
}

// ============ k_out: out = [s1|effect|x] @ out_w + out_b (fp32, x2) ============
// tile 64 x 128; grid (256, 2); K=1536 in pairs
__global__ __launch_bounds__(256) void k_out(
    const u16* __restrict__ s1b, const u16* __restrict__ effb,
    const float* __restrict__ x, const u16* __restrict__ outT,
    const float* __restrict__ out_b, float* __restrict__ out, int dup)
{
  __shared__ __align__(16) u16 smA[2][4 * 64 * 8];   // 2 x 4 KB
  __shared__ __align__(16) u16 smB[2][8 * 64 * 8];   // 2 x 8 KB
  const int tid = threadIdx.x, wv = tid >> 6, lane = tid & 63;
  const int cl = lane & 15, quad = lane >> 4;
  const int row0 = blockIdx.x * 64;
  const int nb = blockIdx.y;
  f32x4 acc[8];
#pragma unroll
  for (int u = 0; u < 8; ++u) acc[u] = (f32x4){0.f, 0.f, 0.f, 0.f};

  for (int kk = 0; kk < 24; ++kk) {
    const int kc0 = kk * 2;
    __syncthreads();
    if (kc0 < 16) {
#pragma unroll
      for (int p = 0; p < 2; ++p) {
        const int kc = kc0 + p;
        const u16* base = (kc < 8) ? s1b : effb;
        const int kof = (kc & 7) * 32;
        glds16(base + (size_t)(row0 + wv * 16 + (lane & 15)) * FC + kof + (lane >> 4) * 8,
               &smA[p][wv * 512]);
      }
    } else {
      const int t = tid >> 6, ll = tid & 63;
      const float* src0 = x + (size_t)(row0 + t * 16 + (ll & 15)) * MX + (ll >> 4) * 8;
#pragma unroll
      for (int p = 0; p < 2; ++p) {
        const float* src = src0 + (kc0 + p - 16) * 32;
        float4 a = *(const float4*)src, b = *(const float4*)(src + 4);
        uint4 w; w.x = pk2(a.x, a.y); w.y = pk2(a.z, a.w); w.z = pk2(b.x, b.y); w.w = pk2(b.z, b.w);
        *(uint4*)&smA[p][(size_t)tid * 8] = w;
      }
    }
#pragma unroll
    for (int p = 0; p < 2; ++p)
#pragma unroll
      for (int i = 0; i < 2; ++i) {
        const int u = wv * 2 + i;
        glds16(outT + ((size_t)((nb * 8 + u) * 48 + kc0 + p) * 64 + lane) * 8, &smB[p][u * 512]);
      }
    __syncthreads();
#pragma unroll
    for (int p = 0; p < 2; ++p) {
      bf16x8 af = frag_ld(&smA[p][(wv * 64 + lane) * 8]);
#pragma unroll
      for (int u = 0; u < 8; ++u) {
        bf16x8 bf = frag_ld(&smB[p][(u * 64 + lane) * 8]);
        acc[u] = __builtin_amdgcn_mfma_f32_16x16x32_bf16(af, bf, acc[u], 0, 0, 0);
      }
    }
  }
  float bias[8];
#pragma unroll
  for (int u = 0; u < 8; ++u) bias[u] = out_b[nb * 128 + u * 16 + cl];
#pragma unroll
  for (int r4 = 0; r4 < 4; ++r4) {
    const int row = row0 + wv * 16 + quad * 4 + r4;
#pragma unroll
    for (int u = 0; u < 8; ++u) {
      const float o = acc[u][r4] + bias[u];
      const size_t off = (size_t)row * FC + nb * 128 + u * 16 + cl;
      out[off] = o;
      if (dup) out[(size_t)NROW * FC + off] = o;
    }
  }
}

extern "C" void kernel_launch(void* const* d_in, const int* in_sizes, int n_in,
                              void* d_out, int out_size, void* d_ws, size_t ws_size,
                              hipStream_t stream) {
  const float* x      = (const float*)d_in[0];
  const float* state  = (const float*)d_in[1];
  const float* enc_w  = (const float*)d_in[2];
  const float* enc_b  = (const float*)d_in[3];
  const float* enc_g  = (const float*)d_in[4];
  const float* enc_bb = (const float*)d_in[5];
  const float* core_w = (const float*)d_in[6];
  const float* core_b = (const float*)d_in[7];
  const float* core_g = (const float*)d_in[8];
  const float* core_bb= (const float*)d_in[9];
  const float* ctx_w  = (const float*)d_in[10];
  const float* ctx_b  = (const float*)d_in[11];
  const float* ctx_g  = (const float*)d_in[12];
  const float* ctx_bb = (const float*)d_in[13];
  const float* att1_w = (const float*)d_in[14];
  const float* att1_b = (const float*)d_in[15];
  const float* att_g  = (const float*)d_in[16];
  const float* att_bb = (const float*)d_in[17];
  const float* att2_w = (const float*)d_in[18];
  const float* att2_b = (const float*)d_in[19];
  const float* out_w  = (const float*)d_in[20];
  const float* out_b  = (const float*)d_in[21];

  char* ws = (char*)d_ws;
  float* UV  = (float*)ws;                          // 33,554,432 B
  u16* s1b   = (u16*)(ws + 33554432);               //  8,388,608 B
  u16* effb  = (u16*)(ws + 41943040);               //  8,388,608 B
  u16* encT  = (u16*)(ws + 50331648);               //    262,144 B
  u16* uvT   = (u16*)(ws + 50593792);               //    262,144 B
  u16* ctxT  = (u16*)(ws + 50855936);               //    131,072 B
  u16* attT  = (u16*)(ws + 50987008);               //     65,536 B
  u16* outT  = (u16*)(ws + 51052544);               //    786,432 B
  float* out = (float*)d_out;
  const int dup = (out_size >= 2 * NROW * FC) ? 1 : 0;

  k_prep<<<dim3(368), 256, 0, stream>>>(enc_w, core_w, ctx_w, att1_w, out_w,
                                        encT, uvT, ctxT, attT, outT);
  k_enc<<<dim3(NROW / 32), 256, 0, stream>>>(state, encT, enc_b, enc_g, enc_bb, s1b);
  k_uv <<<dim3(NROW / 64, 4), 256, 0, stream>>>(s1b, uvT, UV);
  k_pair<<<dim3(NGRP), 256, 0, stream>>>(UV, core_b, core_g, core_bb,
                                         ctxT, ctx_b, ctx_g, ctx_bb,
                                         attT, att1_b, att_g, att_bb,
                                         att2_w, att2_b, effb);
  k_out<<<dim3(NROW / 64, 2), 256, 0, stream>>>(s1b, effb, x, outT, out_b, out, dup);
}